// Round 1
// baseline (5808.171 us; speedup 1.0000x reference)
//
#include <hip/hip_runtime.h>
#include <stdint.h>

// ---------------------------------------------------------------------------
// TSCluster: 3x TransformerEncoderLayer (post-norm, relu) + cluster softmax +
// sequential HMM recursion.  N*P=131072 tokens, D=512, H=8, DFF=2048, C=32.
// Strategy: bf16 activations + bf16 MFMA GEMMs (f32 accum), f32 LN/softmax.
// ---------------------------------------------------------------------------

typedef __bf16 bf16;
typedef __bf16 bf16x2 __attribute__((ext_vector_type(2)));
typedef __bf16 bf16x4 __attribute__((ext_vector_type(4)));
typedef __bf16 bf16x8 __attribute__((ext_vector_type(8)));
typedef float  f32x4  __attribute__((ext_vector_type(4)));
typedef float  f32x2  __attribute__((ext_vector_type(2)));

#define EPSF 1e-10f
#define NROWS 131072L   // N*P

__device__ __forceinline__ float bflo(uint32_t u){ return __uint_as_float(u << 16); }
__device__ __forceinline__ float bfhi(uint32_t u){ return __uint_as_float(u & 0xffff0000u); }

__device__ __forceinline__ void gload_lds16(const bf16* g, bf16* l){
  __builtin_amdgcn_global_load_lds((const __attribute__((address_space(1))) uint32_t*)g,
                                   (__attribute__((address_space(3))) uint32_t*)l,
                                   16, 0, 0);
}

// ---------------------------------------------------------------------------
// f32 -> bf16 convert (vectorized, grid-stride)
__global__ void k_f2bf(const float* __restrict__ in, bf16* __restrict__ out, long n){
  const long stride = (long)gridDim.x * blockDim.x * 4;
  for (long i = ((long)blockIdx.x * blockDim.x + threadIdx.x) * 4; i < n; i += stride){
    f32x4 v = *(const f32x4*)(in + i);
    bf16x4 o = { (bf16)v[0], (bf16)v[1], (bf16)v[2], (bf16)v[3] };
    *(bf16x4*)(out + i) = o;
  }
}

// bf16 -> f32 convert
__global__ void k_bf2f(const bf16* __restrict__ in, float* __restrict__ out, long n){
  const long stride = (long)gridDim.x * blockDim.x * 4;
  for (long i = ((long)blockIdx.x * blockDim.x + threadIdx.x) * 4; i < n; i += stride){
    bf16x4 v = *(const bf16x4*)(in + i);
    f32x4 o = { (float)v[0], (float)v[1], (float)v[2], (float)v[3] };
    *(f32x4*)(out + i) = o;
  }
}

// ---------------------------------------------------------------------------
// GEMM: C[m,n] = sum_k A[m,k] * W[n,k] + bias[n]   (B^T layout, both K-contig)
// 128x128 tile, BK=32, 4 waves, mfma_f32_16x16x32_bf16, global_load_lds(16B).
// grid = (N/128, M/128); M,N % 128 == 0, K % 32 == 0.
template<int RELU>
__global__ __launch_bounds__(256)
void gemm_bt(const bf16* __restrict__ A, long lda,
             const bf16* __restrict__ W,
             const float* __restrict__ bias,
             bf16* __restrict__ Cb, long ldc, long K)
{
  const int tid  = threadIdx.x;
  const int wid  = tid >> 6;
  const int lane = tid & 63;
  const long bm = (long)blockIdx.y * 128;
  const long bn = (long)blockIdx.x * 128;

  __shared__ __align__(16) bf16 As[128 * 32];
  __shared__ __align__(16) bf16 Bs[128 * 32];

  f32x4 acc[4][4];
#pragma unroll
  for (int i = 0; i < 4; i++)
#pragma unroll
    for (int j = 0; j < 4; j++) acc[i][j] = (f32x4){0.f, 0.f, 0.f, 0.f};

  // staging: wave w covers tile rows [w*32, w*32+32); lane l -> row w*32+l/4,
  // 16B chunk (l%4).  LDS linear dest == wave base + lane*16B (row-major [128][32]).
  const int srow = wid * 32 + (lane >> 2);
  const int scol = (lane & 3) * 8;
  const bf16* Ag0 = A + (bm + srow) * lda + scol;
  const bf16* Ag1 = Ag0 + 16 * lda;
  const bf16* Wg0 = W + (bn + srow) * K + scol;
  const bf16* Wg1 = Wg0 + 16 * K;
  bf16* Asl0 = &As[(wid * 32) * 32];
  bf16* Asl1 = &As[(wid * 32 + 16) * 32];
  bf16* Bsl0 = &Bs[(wid * 32) * 32];
  bf16* Bsl1 = &Bs[(wid * 32 + 16) * 32];

  const int fr = lane & 15;          // fragment row (A) / col (B,D)
  const int fk = (lane >> 4) * 8;    // k offset of this lane's 8 elems
  const int ar = (wid >> 1) * 64;    // wave's output row block
  const int bc = (wid & 1) * 64;     // wave's output col block

  for (long k0 = 0; k0 < K; k0 += 32){
    gload_lds16(Ag0 + k0, Asl0);
    gload_lds16(Ag1 + k0, Asl1);
    gload_lds16(Wg0 + k0, Bsl0);
    gload_lds16(Wg1 + k0, Bsl1);
    __syncthreads();                 // drains vmcnt -> staging visible
    bf16x8 a[4], b[4];
#pragma unroll
    for (int i = 0; i < 4; i++) a[i] = *(const bf16x8*)&As[(ar + i * 16 + fr) * 32 + fk];
#pragma unroll
    for (int j = 0; j < 4; j++) b[j] = *(const bf16x8*)&Bs[(bc + j * 16 + fr) * 32 + fk];
#pragma unroll
    for (int i = 0; i < 4; i++)
#pragma unroll
      for (int j = 0; j < 4; j++)
        acc[i][j] = __builtin_amdgcn_mfma_f32_16x16x32_bf16(a[i], b[j], acc[i][j], 0, 0, 0);
    __syncthreads();                 // all waves done reading before next stage
  }

  const int fg = lane >> 4;
#pragma unroll
  for (int j = 0; j < 4; j++){
    const long col = bn + bc + j * 16 + fr;
    const float bv = bias[col];
#pragma unroll
    for (int i = 0; i < 4; i++){
#pragma unroll
      for (int r = 0; r < 4; r++){
        const long row = bm + ar + i * 16 + fg * 4 + r;   // D: row=(l>>4)*4+reg, col=l&15
        float v = acc[i][j][r] + bv;
        if (RELU) v = fmaxf(v, 0.f);
        Cb[row * ldc + col] = (bf16)v;
      }
    }
  }
}

// ---------------------------------------------------------------------------
// Fused attention for one (n, h): Q,K,V are 64x64 bf16 slices of the qkv buffer
// [NROWS][1536].  O overwrites the Q slice.  scale = 1/sqrt(64) = 0.125.
__global__ __launch_bounds__(256)
void attention(bf16* __restrict__ qkv)
{
  const int blk = blockIdx.x;
  const long n = blk >> 3;
  const int h  = blk & 7;
  const int tid = threadIdx.x;
  const int wid = tid >> 6, lane = tid & 63;

  __shared__ __align__(16) bf16 Qs[64][72];   // pad 72: breaks stride-128B conflicts
  __shared__ __align__(16) bf16 Ks[64][72];
  __shared__ __align__(16) bf16 Vt[64][72];   // V transposed: Vt[e][q]

  bf16* base = qkv + n * 64 * 1536 + h * 64;

  for (int c = tid; c < 512; c += 256){
    const int row = c >> 3, col = (c & 7) * 8;
    const long go = (long)row * 1536 + col;
    *(bf16x8*)&Qs[row][col] = *(const bf16x8*)(base + go);
    *(bf16x8*)&Ks[row][col] = *(const bf16x8*)(base + 512 + go);
    bf16x8 v = *(const bf16x8*)(base + 1024 + go);
#pragma unroll
    for (int e = 0; e < 8; e++) Vt[col + e][row] = v[e];
  }
  __syncthreads();

  const int fr = lane & 15, fg = lane >> 4;
  f32x4 sacc[4];
#pragma unroll
  for (int j = 0; j < 4; j++) sacc[j] = (f32x4){0.f, 0.f, 0.f, 0.f};
#pragma unroll
  for (int ks = 0; ks < 2; ks++){
    bf16x8 a = *(const bf16x8*)&Qs[wid * 16 + fr][ks * 32 + fg * 8];
#pragma unroll
    for (int j = 0; j < 4; j++){
      bf16x8 bb = *(const bf16x8*)&Ks[j * 16 + fr][ks * 32 + fg * 8];
      sacc[j] = __builtin_amdgcn_mfma_f32_16x16x32_bf16(a, bb, sacc[j], 0, 0, 0);
    }
  }

  // softmax over the 64 cols of each of this lane-group's 4 rows
  float pv[4][4];
#pragma unroll
  for (int r = 0; r < 4; r++){
    float m = -1e30f;
#pragma unroll
    for (int j = 0; j < 4; j++) m = fmaxf(m, sacc[j][r]);
#pragma unroll
    for (int msk = 1; msk < 16; msk <<= 1) m = fmaxf(m, __shfl_xor(m, msk));
    float s = 0.f;
#pragma unroll
    for (int j = 0; j < 4; j++){
      float p = __expf((sacc[j][r] - m) * 0.125f);
      pv[j][r] = p; s += p;
    }
#pragma unroll
    for (int msk = 1; msk < 16; msk <<= 1) s += __shfl_xor(s, msk);
    const float inv = 1.f / s;
#pragma unroll
    for (int j = 0; j < 4; j++) pv[j][r] *= inv;
  }

  // write P into Qs (each wave only touches its own 16 rows)
#pragma unroll
  for (int j = 0; j < 4; j++)
#pragma unroll
    for (int r = 0; r < 4; r++)
      Qs[wid * 16 + fg * 4 + r][j * 16 + fr] = (bf16)pv[j][r];
  __syncthreads();

  f32x4 oacc[4];
#pragma unroll
  for (int j = 0; j < 4; j++) oacc[j] = (f32x4){0.f, 0.f, 0.f, 0.f};
#pragma unroll
  for (int ks = 0; ks < 2; ks++){
    bf16x8 a = *(const bf16x8*)&Qs[wid * 16 + fr][ks * 32 + fg * 8];
#pragma unroll
    for (int j = 0; j < 4; j++){
      bf16x8 bb = *(const bf16x8*)&Vt[j * 16 + fr][ks * 32 + fg * 8];
      oacc[j] = __builtin_amdgcn_mfma_f32_16x16x32_bf16(a, bb, oacc[j], 0, 0, 0);
    }
  }
#pragma unroll
  for (int j = 0; j < 4; j++)
#pragma unroll
    for (int r = 0; r < 4; r++)
      base[(long)(wid * 16 + fg * 4 + r) * 1536 + j * 16 + fr] = (bf16)oacc[j][r];
}

// ---------------------------------------------------------------------------
// y = LayerNorm(x + o) * w + b ; one block per row of 512, f32 math, bf16 I/O.
__global__ __launch_bounds__(256)
void resid_ln(const bf16* __restrict__ X, const bf16* __restrict__ O,
              const float* __restrict__ w, const float* __restrict__ b,
              bf16* __restrict__ Y)
{
  const long row = blockIdx.x;
  const int tid = threadIdx.x, lane = tid & 63, wid = tid >> 6;
  const uint32_t xu = ((const uint32_t*)(X + row * 512))[tid];
  const uint32_t ou = ((const uint32_t*)(O + row * 512))[tid];
  const float s0 = bflo(xu) + bflo(ou);
  const float s1 = bfhi(xu) + bfhi(ou);
  float sum = s0 + s1, sq = s0 * s0 + s1 * s1;
#pragma unroll
  for (int m = 1; m < 64; m <<= 1){ sum += __shfl_xor(sum, m); sq += __shfl_xor(sq, m); }
  __shared__ float red[8];
  if (lane == 0){ red[wid] = sum; red[4 + wid] = sq; }
  __syncthreads();
  sum = red[0] + red[1] + red[2] + red[3];
  sq  = red[4] + red[5] + red[6] + red[7];
  const float mean = sum * (1.f / 512.f);
  const float var  = sq * (1.f / 512.f) - mean * mean;
  const float rs   = rsqrtf(var + 1e-5f);
  const f32x2 wv = *(const f32x2*)(w + 2 * tid);
  const f32x2 bv = *(const f32x2*)(b + 2 * tid);
  bf16x2 o2 = { (bf16)((s0 - mean) * rs * wv[0] + bv[0]),
                (bf16)((s1 - mean) * rs * wv[1] + bv[1]) };
  *(bf16x2*)(Y + row * 512 + 2 * tid) = o2;
}

// ---------------------------------------------------------------------------
// mu = tanh(mus) -> bf16 [32][512]; munorm[c] = ||mu_c||^2 (f32).  grid=32.
__global__ __launch_bounds__(256)
void k_mu(const float* __restrict__ mus, bf16* __restrict__ mubf, float* __restrict__ munorm)
{
  const int c = blockIdx.x, tid = threadIdx.x, lane = tid & 63, wid = tid >> 6;
  const f32x2 v = *(const f32x2*)(mus + c * 512 + 2 * tid);
  const float t0 = tanhf(v[0]), t1 = tanhf(v[1]);
  bf16x2 o2 = { (bf16)t0, (bf16)t1 };
  *(bf16x2*)(mubf + c * 512 + 2 * tid) = o2;
  float sq = t0 * t0 + t1 * t1;
#pragma unroll
  for (int m = 1; m < 64; m <<= 1) sq += __shfl_xor(sq, m);
  __shared__ float red[4];
  if (lane == 0) red[wid] = sq;
  __syncthreads();
  if (tid == 0) munorm[c] = red[0] + red[1] + red[2] + red[3];
}

// ---------------------------------------------------------------------------
// log_za[row][c] = log(softmax_c(-dist/10) + 1e-10), dist = ||x||^2+||mu||^2-2 x.mu
// block handles 16 rows; mu staged once in LDS.  grid = NROWS/16.
__global__ __launch_bounds__(256)
void cluster_logza(const bf16* __restrict__ X, const bf16* __restrict__ MU,
                   const float* __restrict__ munorm, float* __restrict__ out)
{
  const int tid = threadIdx.x, lane = tid & 63, wid = tid >> 6;
  __shared__ __align__(16) bf16 mus[32][512];
  __shared__ float xs[512];
  __shared__ float red[4];
  __shared__ float dots[32];
  for (int c = tid; c < 2048; c += 256){
    const int r = c >> 6, col = (c & 63) * 8;
    *(bf16x8*)&mus[r][col] = *(const bf16x8*)(MU + r * 512 + col);
  }
  const int cc = tid >> 3, seg = tid & 7;
  const long row0 = (long)blockIdx.x * 16;
  __syncthreads();
  for (int rr = 0; rr < 16; rr++){
    const long row = row0 + rr;
    const uint32_t u = ((const uint32_t*)(X + row * 512))[tid];
    const float a = bflo(u), bb = bfhi(u);
    xs[2 * tid] = a; xs[2 * tid + 1] = bb;
    float sq = a * a + bb * bb;
#pragma unroll
    for (int m = 1; m < 64; m <<= 1) sq += __shfl_xor(sq, m);
    if (lane == 0) red[wid] = sq;
    __syncthreads();
    const float xn = red[0] + red[1] + red[2] + red[3];
    // dot(x, mu_cc): 8 chunks of 8, chunk index jj*8+seg keeps banks spread
    float p = 0.f;
#pragma unroll
    for (int jj = 0; jj < 8; jj++){
      const int col = jj * 64 + seg * 8;
      bf16x8 m8 = *(const bf16x8*)&mus[cc][col];
      const float* xv = &xs[col];
#pragma unroll
      for (int e = 0; e < 8; e++) p += xv[e] * (float)m8[e];
    }
#pragma unroll
    for (int m = 1; m < 8; m <<= 1) p += __shfl_xor(p, m);
    if (seg == 0) dots[cc] = p;
    __syncthreads();
    if (tid < 32){
      const float dist = xn + munorm[tid] - 2.f * dots[tid];
      const float lg = -dist * 0.1f;       // 1/TEMP
      float mx = lg;
#pragma unroll
      for (int m = 1; m < 32; m <<= 1) mx = fmaxf(mx, __shfl_xor(mx, m, 32));
      const float z = __expf(lg - mx);
      float s = z;
#pragma unroll
      for (int m = 1; m < 32; m <<= 1) s += __shfl_xor(s, m, 32);
      out[row * 32 + tid] = logf(z / s + EPSF);
    }
    __syncthreads();
  }
}

// ---------------------------------------------------------------------------
// HMM recursion over P=64 patches.  32 lanes per n-row; 8 rows per block.
__global__ __launch_bounds__(256)
void k_hmm(const float* __restrict__ lza, const float* __restrict__ pi,
           const float* __restrict__ A, float* __restrict__ cp, float* __restrict__ ent)
{
  __shared__ float As[32][33];
  const int tid = threadIdx.x;
  for (int i = tid; i < 1024; i += 256) As[i >> 5][i & 31] = A[i];
  __syncthreads();
  const int j = tid & 31;
  const long n = (long)blockIdx.x * 8 + (tid >> 5);
  const float* lz = lza + n * 2048;

  float c = logf(pi[j] + EPSF) + lz[j];
  {
    float mx = c;
#pragma unroll
    for (int m = 1; m < 32; m <<= 1) mx = fmaxf(mx, __shfl_xor(mx, m, 32));
    float z = __expf(c - mx), s = z;
#pragma unroll
    for (int m = 1; m < 32; m <<= 1) s += __shfl_xor(s, m, 32);
    c = z / s;
  }
  cp[n * 2048 + j] = c;
  float ea = -c * logf(c + EPSF);

  for (int p = 1; p < 64; p++){
    float y = 0.f;
#pragma unroll
    for (int i = 0; i < 32; i++) y += __shfl(c, i, 32) * As[i][j];
    float t = logf(y + EPSF) + lz[p * 32 + j];
    float mx = t;
#pragma unroll
    for (int m = 1; m < 32; m <<= 1) mx = fmaxf(mx, __shfl_xor(mx, m, 32));
    float z = __expf(t - mx), s = z;
#pragma unroll
    for (int m = 1; m < 32; m <<= 1) s += __shfl_xor(s, m, 32);
    c = z / s;
    cp[n * 2048 + p * 32 + j] = c;
    ea += -c * logf(c + EPSF);
  }
#pragma unroll
  for (int m = 1; m < 32; m <<= 1) ea += __shfl_xor(ea, m, 32);
  if (j == 0) atomicAdd(ent, ea * (1.f / 131072.f));
}

// ---------------------------------------------------------------------------
extern "C" void kernel_launch(void* const* d_in, const int* in_sizes, int n_in,
                              void* d_out, int out_size, void* d_ws, size_t ws_size,
                              hipStream_t stream)
{
  (void)in_sizes; (void)n_in; (void)out_size; (void)ws_size;
  const float* in_series = (const float*)d_in[0];
  const float* pi    = (const float*)d_in[1];
  const float* Amat  = (const float*)d_in[2];
  const float* qkv_w = (const float*)d_in[3];
  const float* qkv_b = (const float*)d_in[4];
  const float* out_w = (const float*)d_in[5];
  const float* out_b = (const float*)d_in[6];
  const float* ln1_w = (const float*)d_in[7];
  const float* ln1_b = (const float*)d_in[8];
  const float* ff1_w = (const float*)d_in[9];
  const float* ff1_b = (const float*)d_in[10];
  const float* ff2_w = (const float*)d_in[11];
  const float* ff2_b = (const float*)d_in[12];
  const float* ln2_w = (const float*)d_in[13];
  const float* ln2_b = (const float*)d_in[14];
  const float* mus   = (const float*)d_in[15];

  // workspace layout (total ~786 MB)
  char* ws = (char*)d_ws;
  bf16* region0 = (bf16*)(ws);                         // 512MB: qkv [131072][1536] / ffmid [131072][2048]
  bf16* xb      = (bf16*)(ws + 536870912L);            // 128MB: activations bf16
  bf16* oproj   = (bf16*)(ws + 671088640L);            // 128MB: block output bf16
  bf16* w_qkv   = (bf16*)(ws + 805306368L);
  bf16* w_out   = (bf16*)(ws + 810024960L);
  bf16* w_ff1   = (bf16*)(ws + 811597824L);
  bf16* w_ff2   = (bf16*)(ws + 817889280L);
  bf16* mubf    = (bf16*)(ws + 824180736L);
  float* munorm = (float*)(ws + 824213504L);
  float* logza  = (float*)(ws);                        // aliases region0 (free after layers)

  float* out_f = (float*)d_out;
  float* cp    = out_f;                  // [131072][32]
  float* emb   = out_f + 4194304L;       // [131072][512]
  float* o_pi  = out_f + 71303168L;
  float* o_A   = out_f + 71303200L;
  float* o_ent = out_f + 71304224L;

  // weight / input conversion
  k_f2bf<<<8192, 256, 0, stream>>>(in_series, xb, 67108864L);
  k_f2bf<<<1024, 256, 0, stream>>>(qkv_w, w_qkv, 2359296L);
  k_f2bf<<<1024, 256, 0, stream>>>(out_w, w_out, 786432L);
  k_f2bf<<<1024, 256, 0, stream>>>(ff1_w, w_ff1, 3145728L);
  k_f2bf<<<1024, 256, 0, stream>>>(ff2_w, w_ff2, 3145728L);
  k_mu<<<32, 256, 0, stream>>>(mus, mubf, munorm);

  for (int l = 0; l < 3; l++){
    // qkv = x @ qkv_w^T + b   -> region0 [131072][1536]
    gemm_bt<0><<<dim3(12, 1024), 256, 0, stream>>>(xb, 512, w_qkv + (long)l * 786432L,
                                                   qkv_b + (long)l * 1536, region0, 1536, 512);
    // fused attention; O overwrites Q slice (cols 0..511)
    attention<<<16384, 256, 0, stream>>>(region0);
    // o @ out_w^T + b -> oproj
    gemm_bt<0><<<dim3(4, 1024), 256, 0, stream>>>(region0, 1536, w_out + (long)l * 262144L,
                                                  out_b + (long)l * 512, oproj, 512, 512);
    resid_ln<<<131072, 256, 0, stream>>>(xb, oproj, ln1_w + (long)l * 512, ln1_b + (long)l * 512, xb);
    // ffmid = relu(x @ ff1_w^T + b) -> region0 [131072][2048]
    gemm_bt<1><<<dim3(16, 1024), 256, 0, stream>>>(xb, 512, w_ff1 + (long)l * 1048576L,
                                                   ff1_b + (long)l * 2048, region0, 2048, 512);
    // ffout = ffmid @ ff2_w^T + b -> oproj
    gemm_bt<0><<<dim3(4, 1024), 256, 0, stream>>>(region0, 2048, w_ff2 + (long)l * 1048576L,
                                                  ff2_b + (long)l * 512, oproj, 512, 2048);
    resid_ln<<<131072, 256, 0, stream>>>(xb, oproj, ln2_w + (long)l * 512, ln2_b + (long)l * 512, xb);
  }

  // emb_ts output (f32)
  k_bf2f<<<8192, 256, 0, stream>>>(xb, emb, 67108864L);
  // cluster softmax logs
  cluster_logza<<<8192, 256, 0, stream>>>(xb, mubf, munorm, logza);
  // HMM recursion + entropy
  hipMemsetAsync(o_ent, 0, 4, stream);
  k_hmm<<<256, 256, 0, stream>>>(logza, pi, Amat, cp, o_ent);
  // pass-through outputs
  hipMemcpyAsync(o_pi, pi, 32 * sizeof(float), hipMemcpyDeviceToDevice, stream);
  hipMemcpyAsync(o_A, Amat, 1024 * sizeof(float), hipMemcpyDeviceToDevice, stream);
}

// Round 2
// 4834.515 us; speedup vs baseline: 1.2014x; 1.2014x over previous
//
#include <hip/hip_runtime.h>
#include <stdint.h>

// ---------------------------------------------------------------------------
// TSCluster: 3x TransformerEncoderLayer (post-norm, relu) + cluster softmax +
// sequential HMM recursion.  N*P=131072 tokens, D=512, H=8, DFF=2048, C=32.
// bf16 activations + bf16 MFMA GEMMs (f32 accum), f32 LN/softmax.
// GEMM: 256x256 tile, BK=64, 8 waves, 4-phase/K-tile counted-vmcnt pipeline,
// XOR-swizzled LDS (inverse swizzle on global_load_lds source).
// ---------------------------------------------------------------------------

typedef __bf16 bf16;
typedef __bf16 bf16x2 __attribute__((ext_vector_type(2)));
typedef __bf16 bf16x4 __attribute__((ext_vector_type(4)));
typedef __bf16 bf16x8 __attribute__((ext_vector_type(8)));
typedef float  f32x4  __attribute__((ext_vector_type(4)));
typedef float  f32x2  __attribute__((ext_vector_type(2)));

#define EPSF 1e-10f
#define NROWS 131072L   // N*P

__device__ __forceinline__ float bflo(uint32_t u){ return __uint_as_float(u << 16); }
__device__ __forceinline__ float bfhi(uint32_t u){ return __uint_as_float(u & 0xffff0000u); }

__device__ __forceinline__ void gload_lds16(const bf16* g, bf16* l){
  __builtin_amdgcn_global_load_lds((const __attribute__((address_space(1))) uint32_t*)g,
                                   (__attribute__((address_space(3))) uint32_t*)l,
                                   16, 0, 0);
}

// ---------------------------------------------------------------------------
__global__ void k_f2bf(const float* __restrict__ in, bf16* __restrict__ out, long n){
  const long stride = (long)gridDim.x * blockDim.x * 4;
  for (long i = ((long)blockIdx.x * blockDim.x + threadIdx.x) * 4; i < n; i += stride){
    f32x4 v = *(const f32x4*)(in + i);
    bf16x4 o = { (bf16)v[0], (bf16)v[1], (bf16)v[2], (bf16)v[3] };
    *(bf16x4*)(out + i) = o;
  }
}

__global__ void k_bf2f(const bf16* __restrict__ in, float* __restrict__ out, long n){
  const long stride = (long)gridDim.x * blockDim.x * 4;
  for (long i = ((long)blockIdx.x * blockDim.x + threadIdx.x) * 4; i < n; i += stride){
    bf16x4 v = *(const bf16x4*)(in + i);
    f32x4 o = { (float)v[0], (float)v[1], (float)v[2], (float)v[3] };
    *(f32x4*)(out + i) = o;
  }
}

// ---------------------------------------------------------------------------
// 256x256x64 8-wave GEMM: C[m,n] = A[m,k] * W[n,k] + bias[n]  (both K-contig)
// Phases per K-tile: (rh,ch) quadrants; staging tile t+1 during tile t with
// counted vmcnt; LDS granule-XOR swizzle, inverse-swizzled global source.

#define MFMA_PH(RH, CH)                                                       \
  {                                                                           \
    __builtin_amdgcn_s_setprio(1);                                            \
    _Pragma("unroll")                                                         \
    for (int i2 = 0; i2 < 4; i2++) {                                          \
      _Pragma("unroll")                                                       \
      for (int j2 = 0; j2 < 2; j2++) {                                        \
        acc[(RH)*4+i2][(CH)*2+j2] = __builtin_amdgcn_mfma_f32_16x16x32_bf16(  \
            a[i2][0], b[CH][j2][0], acc[(RH)*4+i2][(CH)*2+j2], 0, 0, 0);      \
        acc[(RH)*4+i2][(CH)*2+j2] = __builtin_amdgcn_mfma_f32_16x16x32_bf16(  \
            a[i2][1], b[CH][j2][1], acc[(RH)*4+i2][(CH)*2+j2], 0, 0, 0);      \
      }                                                                       \
    }                                                                         \
    __builtin_amdgcn_s_setprio(0);                                            \
  }

#define RD_A(RH)                                                              \
  _Pragma("unroll")                                                           \
  for (int i2 = 0; i2 < 4; i2++) {                                            \
    a[i2][0] = *(const bf16x8*)&Ac[(aRow + (RH)*64 + i2*16) * 64 + sl0];      \
    a[i2][1] = *(const bf16x8*)&Ac[(aRow + (RH)*64 + i2*16) * 64 + sl1];      \
  }

#define RD_B(CH)                                                              \
  _Pragma("unroll")                                                           \
  for (int j2 = 0; j2 < 2; j2++) {                                            \
    b[CH][j2][0] = *(const bf16x8*)&Bc[(bRow + (CH)*32 + j2*16) * 64 + sl0];  \
    b[CH][j2][1] = *(const bf16x8*)&Bc[(bRow + (CH)*32 + j2*16) * 64 + sl1];  \
  }

#define ISSUE_A(dst, BI, KK) \
  gload_lds16(gA + (long)(BI)*64*lda + (KK), (dst) + (BI)*4096 + wslice)
#define ISSUE_B(dst, BI, KK) \
  gload_lds16(gB + (long)(BI)*64*K   + (KK), (dst) + (BI)*4096 + wslice)

#define WAITV(N)  asm volatile("s_waitcnt vmcnt(" #N ")" ::: "memory")
#define WAITL0    asm volatile("s_waitcnt lgkmcnt(0)" ::: "memory")
#define BARRIER   { __builtin_amdgcn_s_barrier(); asm volatile("" ::: "memory"); }

template<int RELU>
__global__ __launch_bounds__(512, 2)
void gemm256(const bf16* __restrict__ A, long lda,
             const bf16* __restrict__ W,
             const float* __restrict__ bias,
             bf16* __restrict__ Cb, long K, int nbx)
{
  const int tid  = threadIdx.x;
  const int wid  = tid >> 6;
  const int lane = tid & 63;
  const int wr = wid >> 2, wc = wid & 3;
  const long ldc = (long)nbx * 256;

  // XCD-chunked block swizzle (nwg % 8 == 0 for all our shapes)
  const unsigned nwg = gridDim.x;
  const unsigned q   = nwg >> 3;
  const unsigned swz = (blockIdx.x & 7) * q + (blockIdx.x >> 3);
  const unsigned bx  = swz % (unsigned)nbx;
  const unsigned by  = swz / (unsigned)nbx;
  const long bm = (long)by * 256;
  const long bn = (long)bx * 256;

  __shared__ __align__(16) bf16 smem[65536];   // 128 KiB
  bf16* const As0 = smem;
  bf16* const Bs0 = smem + 16384;
  bf16* const As1 = smem + 32768;
  bf16* const Bs1 = smem + 49152;

  // staging constants: issue = 64 rows x 64 k (8KB), wave slice = 8 rows (1KB)
  const int srow   = wid * 8 + (lane >> 3);
  const int scol   = ((lane & 7) ^ ((lane >> 3) & 7)) * 8;   // inverse swizzle
  const int wslice = wid * 512;
  const bf16* gA = A + (bm + srow) * lda + scol;
  const bf16* gB = W + (bn + srow) * K   + scol;

  // fragment-read constants
  const int fr = lane & 15, fg = lane >> 4;
  const int aRow = wr * 128 + fr;
  const int bRow = wc * 64  + fr;
  const int sl0 = ((0 + fg) ^ (fr & 7)) * 8;
  const int sl1 = ((4 + fg) ^ (fr & 7)) * 8;

  f32x4 acc[8][4];
#pragma unroll
  for (int i = 0; i < 8; i++)
#pragma unroll
    for (int j = 0; j < 4; j++) acc[i][j] = (f32x4){0.f, 0.f, 0.f, 0.f};

  bf16x8 a[4][2];
  bf16x8 b[2][2][2];

  const int nt = (int)(K >> 6);

  // ---- prologue: stage tile 0 into buf0 (issue order = pos1..8) ----
  ISSUE_A(As0, 0, 0); ISSUE_A(As0, 2, 0);
  ISSUE_B(Bs0, 0, 0); ISSUE_B(Bs0, 1, 0);
  ISSUE_B(Bs0, 2, 0); ISSUE_B(Bs0, 3, 0);
  ISSUE_A(As0, 1, 0); ISSUE_A(As0, 3, 0);
  WAITV(2);          // pos1-6 (A0,A2,B0..B3) landed; A1,A3 may float
  BARRIER;

  for (int t = 0; t < nt; t++){
    bf16* const Ac = (t & 1) ? As1 : As0;
    bf16* const Bc = (t & 1) ? Bs1 : Bs0;
    bf16* const An = (t & 1) ? As0 : As1;
    bf16* const Bn = (t & 1) ? Bs0 : Bs1;
    const bool stage = (t + 1 < nt);
    const long kn = (long)(t + 1) << 6;

    // ---- phase 0: quadrant (rh0, ch0) ----
    RD_A(0); RD_B(0);
    if (stage){ ISSUE_A(An, 0, kn); ISSUE_A(An, 2, kn);
                ISSUE_B(Bn, 0, kn); ISSUE_B(Bn, 1, kn); }
    BARRIER;
    WAITL0;
    MFMA_PH(0, 0);
    BARRIER;

    // ---- phase 1: (rh0, ch1) ----
    RD_B(1);
    if (stage){ ISSUE_B(Bn, 2, kn); ISSUE_B(Bn, 3, kn); WAITV(6); }
    else      { WAITV(0); }
    BARRIER;
    WAITL0;
    MFMA_PH(0, 1);
    BARRIER;

    // ---- phase 2: (rh1, ch0) ----
    RD_A(1);
    if (stage){ ISSUE_A(An, 1, kn); ISSUE_A(An, 3, kn); }
    BARRIER;
    WAITL0;
    MFMA_PH(1, 0);
    BARRIER;

    // ---- phase 3: (rh1, ch1) ----
    WAITV(2);        // next tile pos1-6 landed (no-op on last tile)
    BARRIER;
    MFMA_PH(1, 1);
    BARRIER;
  }

  // ---- epilogue ----
#pragma unroll
  for (int j = 0; j < 4; j++){
    const long col = bn + wc * 64 + j * 16 + fr;
    const float bv = bias[col];
#pragma unroll
    for (int i = 0; i < 8; i++){
#pragma unroll
      for (int r = 0; r < 4; r++){
        const long row = bm + wr * 128 + i * 16 + fg * 4 + r;
        float v = acc[i][j][r] + bv;
        if (RELU) v = fmaxf(v, 0.f);
        Cb[row * ldc + col] = (bf16)v;
      }
    }
  }
}

// ---------------------------------------------------------------------------
// Fused attention for one (n, h): Q,K,V are 64x64 bf16 slices of the qkv buffer
// [NROWS][1536].  O overwrites the Q slice.  scale = 1/sqrt(64) = 0.125.
__global__ __launch_bounds__(256)
void attention(bf16* __restrict__ qkv)
{
  const int blk = blockIdx.x;
  const long n = blk >> 3;
  const int h  = blk & 7;
  const int tid = threadIdx.x;
  const int wid = tid >> 6, lane = tid & 63;

  __shared__ __align__(16) bf16 Qs[64][72];
  __shared__ __align__(16) bf16 Ks[64][72];
  __shared__ __align__(16) bf16 Vt[64][72];

  bf16* base = qkv + n * 64 * 1536 + h * 64;

  for (int c = tid; c < 512; c += 256){
    const int row = c >> 3, col = (c & 7) * 8;
    const long go = (long)row * 1536 + col;
    *(bf16x8*)&Qs[row][col] = *(const bf16x8*)(base + go);
    *(bf16x8*)&Ks[row][col] = *(const bf16x8*)(base + 512 + go);
    bf16x8 v = *(const bf16x8*)(base + 1024 + go);
#pragma unroll
    for (int e = 0; e < 8; e++) Vt[col + e][row] = v[e];
  }
  __syncthreads();

  const int fr = lane & 15, fg = lane >> 4;
  f32x4 sacc[4];
#pragma unroll
  for (int j = 0; j < 4; j++) sacc[j] = (f32x4){0.f, 0.f, 0.f, 0.f};
#pragma unroll
  for (int ks = 0; ks < 2; ks++){
    bf16x8 aa = *(const bf16x8*)&Qs[wid * 16 + fr][ks * 32 + fg * 8];
#pragma unroll
    for (int j = 0; j < 4; j++){
      bf16x8 bb = *(const bf16x8*)&Ks[j * 16 + fr][ks * 32 + fg * 8];
      sacc[j] = __builtin_amdgcn_mfma_f32_16x16x32_bf16(aa, bb, sacc[j], 0, 0, 0);
    }
  }

  float pv[4][4];
#pragma unroll
  for (int r = 0; r < 4; r++){
    float m = -1e30f;
#pragma unroll
    for (int j = 0; j < 4; j++) m = fmaxf(m, sacc[j][r]);
#pragma unroll
    for (int msk = 1; msk < 16; msk <<= 1) m = fmaxf(m, __shfl_xor(m, msk));
    float s = 0.f;
#pragma unroll
    for (int j = 0; j < 4; j++){
      float p = __expf((sacc[j][r] - m) * 0.125f);
      pv[j][r] = p; s += p;
    }
#pragma unroll
    for (int msk = 1; msk < 16; msk <<= 1) s += __shfl_xor(s, msk);
    const float inv = 1.f / s;
#pragma unroll
    for (int j = 0; j < 4; j++) pv[j][r] *= inv;
  }

#pragma unroll
  for (int j = 0; j < 4; j++)
#pragma unroll
    for (int r = 0; r < 4; r++)
      Qs[wid * 16 + fg * 4 + r][j * 16 + fr] = (bf16)pv[j][r];
  __syncthreads();

  f32x4 oacc[4];
#pragma unroll
  for (int j = 0; j < 4; j++) oacc[j] = (f32x4){0.f, 0.f, 0.f, 0.f};
#pragma unroll
  for (int ks = 0; ks < 2; ks++){
    bf16x8 aa = *(const bf16x8*)&Qs[wid * 16 + fr][ks * 32 + fg * 8];
#pragma unroll
    for (int j = 0; j < 4; j++){
      bf16x8 bb = *(const bf16x8*)&Vt[j * 16 + fr][ks * 32 + fg * 8];
      oacc[j] = __builtin_amdgcn_mfma_f32_16x16x32_bf16(aa, bb, oacc[j], 0, 0, 0);
    }
  }
#pragma unroll
  for (int j = 0; j < 4; j++)
#pragma unroll
    for (int r = 0; r < 4; r++)
      base[(long)(wid * 16 + fg * 4 + r) * 1536 + j * 16 + fr] = (bf16)oacc[j][r];
}

// ---------------------------------------------------------------------------
__global__ __launch_bounds__(256)
void resid_ln(const bf16* __restrict__ X, const bf16* __restrict__ O,
              const float* __restrict__ w, const float* __restrict__ b,
              bf16* __restrict__ Y)
{
  const long row = blockIdx.x;
  const int tid = threadIdx.x, lane = tid & 63, wid = tid >> 6;
  const uint32_t xu = ((const uint32_t*)(X + row * 512))[tid];
  const uint32_t ou = ((const uint32_t*)(O + row * 512))[tid];
  const float s0 = bflo(xu) + bflo(ou);
  const float s1 = bfhi(xu) + bfhi(ou);
  float sum = s0 + s1, sq = s0 * s0 + s1 * s1;
#pragma unroll
  for (int m = 1; m < 64; m <<= 1){ sum += __shfl_xor(sum, m); sq += __shfl_xor(sq, m); }
  __shared__ float red[8];
  if (lane == 0){ red[wid] = sum; red[4 + wid] = sq; }
  __syncthreads();
  sum = red[0] + red[1] + red[2] + red[3];
  sq  = red[4] + red[5] + red[6] + red[7];
  const float mean = sum * (1.f / 512.f);
  const float var  = sq * (1.f / 512.f) - mean * mean;
  const float rs   = rsqrtf(var + 1e-5f);
  const f32x2 wv = *(const f32x2*)(w + 2 * tid);
  const f32x2 bv = *(const f32x2*)(b + 2 * tid);
  bf16x2 o2 = { (bf16)((s0 - mean) * rs * wv[0] + bv[0]),
                (bf16)((s1 - mean) * rs * wv[1] + bv[1]) };
  *(bf16x2*)(Y + row * 512 + 2 * tid) = o2;
}

// ---------------------------------------------------------------------------
__global__ __launch_bounds__(256)
void k_mu(const float* __restrict__ mus, bf16* __restrict__ mubf, float* __restrict__ munorm)
{
  const int c = blockIdx.x, tid = threadIdx.x, lane = tid & 63, wid = tid >> 6;
  const f32x2 v = *(const f32x2*)(mus + c * 512 + 2 * tid);
  const float t0 = tanhf(v[0]), t1 = tanhf(v[1]);
  bf16x2 o2 = { (bf16)t0, (bf16)t1 };
  *(bf16x2*)(mubf + c * 512 + 2 * tid) = o2;
  float sq = t0 * t0 + t1 * t1;
#pragma unroll
  for (int m = 1; m < 64; m <<= 1) sq += __shfl_xor(sq, m);
  __shared__ float red[4];
  if (lane == 0) red[wid] = sq;
  __syncthreads();
  if (tid == 0) munorm[c] = red[0] + red[1] + red[2] + red[3];
}

// ---------------------------------------------------------------------------
__global__ __launch_bounds__(256)
void cluster_logza(const bf16* __restrict__ X, const bf16* __restrict__ MU,
                   const float* __restrict__ munorm, float* __restrict__ out)
{
  const int tid = threadIdx.x, lane = tid & 63, wid = tid >> 6;
  __shared__ __align__(16) bf16 mus[32][512];
  __shared__ float xs[512];
  __shared__ float red[4];
  __shared__ float dots[32];
  for (int c = tid; c < 2048; c += 256){
    const int r = c >> 6, col = (c & 63) * 8;
    *(bf16x8*)&mus[r][col] = *(const bf16x8*)(MU + r * 512 + col);
  }
  const int cc = tid >> 3, seg = tid & 7;
  const long row0 = (long)blockIdx.x * 16;
  __syncthreads();
  for (int rr = 0; rr < 16; rr++){
    const long row = row0 + rr;
    const uint32_t u = ((const uint32_t*)(X + row * 512))[tid];
    const float aa = bflo(u), bb = bfhi(u);
    xs[2 * tid] = aa; xs[2 * tid + 1] = bb;
    float sq = aa * aa + bb * bb;
#pragma unroll
    for (int m = 1; m < 64; m <<= 1) sq += __shfl_xor(sq, m);
    if (lane == 0) red[wid] = sq;
    __syncthreads();
    const float xn = red[0] + red[1] + red[2] + red[3];
    float p = 0.f;
#pragma unroll
    for (int jj = 0; jj < 8; jj++){
      const int col = jj * 64 + seg * 8;
      bf16x8 m8 = *(const bf16x8*)&mus[cc][col];
      const float* xv = &xs[col];
#pragma unroll
      for (int e = 0; e < 8; e++) p += xv[e] * (float)m8[e];
    }
#pragma unroll
    for (int m = 1; m < 8; m <<= 1) p += __shfl_xor(p, m);
    if (seg == 0) dots[cc] = p;
    __syncthreads();
    if (tid < 32){
      const float dist = xn + munorm[tid] - 2.f * dots[tid];
      const float lg = -dist * 0.1f;
      float mx = lg;
#pragma unroll
      for (int m = 1; m < 32; m <<= 1) mx = fmaxf(mx, __shfl_xor(mx, m, 32));
      const float z = __expf(lg - mx);
      float s = z;
#pragma unroll
      for (int m = 1; m < 32; m <<= 1) s += __shfl_xor(s, m, 32);
      out[row * 32 + tid] = logf(z / s + EPSF);
    }
    __syncthreads();
  }
}

// ---------------------------------------------------------------------------
__global__ __launch_bounds__(256)
void k_hmm(const float* __restrict__ lza, const float* __restrict__ pi,
           const float* __restrict__ A, float* __restrict__ cp, float* __restrict__ ent)
{
  __shared__ float As[32][33];
  const int tid = threadIdx.x;
  for (int i = tid; i < 1024; i += 256) As[i >> 5][i & 31] = A[i];
  __syncthreads();
  const int j = tid & 31;
  const long n = (long)blockIdx.x * 8 + (tid >> 5);
  const float* lz = lza + n * 2048;

  float c = logf(pi[j] + EPSF) + lz[j];
  {
    float mx = c;
#pragma unroll
    for (int m = 1; m < 32; m <<= 1) mx = fmaxf(mx, __shfl_xor(mx, m, 32));
    float z = __expf(c - mx), s = z;
#pragma unroll
    for (int m = 1; m < 32; m <<= 1) s += __shfl_xor(s, m, 32);
    c = z / s;
  }
  cp[n * 2048 + j] = c;
  float ea = -c * logf(c + EPSF);

  for (int p = 1; p < 64; p++){
    float y = 0.f;
#pragma unroll
    for (int i = 0; i < 32; i++) y += __shfl(c, i, 32) * As[i][j];
    float t = logf(y + EPSF) + lz[p * 32 + j];
    float mx = t;
#pragma unroll
    for (int m = 1; m < 32; m <<= 1) mx = fmaxf(mx, __shfl_xor(mx, m, 32));
    float z = __expf(t - mx), s = z;
#pragma unroll
    for (int m = 1; m < 32; m <<= 1) s += __shfl_xor(s, m, 32);
    c = z / s;
    cp[n * 2048 + p * 32 + j] = c;
    ea += -c * logf(c + EPSF);
  }
#pragma unroll
  for (int m = 1; m < 32; m <<= 1) ea += __shfl_xor(ea, m, 32);
  if (j == 0) atomicAdd(ent, ea * (1.f / 131072.f));
}

// ---------------------------------------------------------------------------
extern "C" void kernel_launch(void* const* d_in, const int* in_sizes, int n_in,
                              void* d_out, int out_size, void* d_ws, size_t ws_size,
                              hipStream_t stream)
{
  (void)in_sizes; (void)n_in; (void)out_size; (void)ws_size;
  const float* in_series = (const float*)d_in[0];
  const float* pi    = (const float*)d_in[1];
  const float* Amat  = (const float*)d_in[2];
  const float* qkv_w = (const float*)d_in[3];
  const float* qkv_b = (const float*)d_in[4];
  const float* out_w = (const float*)d_in[5];
  const float* out_b = (const float*)d_in[6];
  const float* ln1_w = (const float*)d_in[7];
  const float* ln1_b = (const float*)d_in[8];
  const float* ff1_w = (const float*)d_in[9];
  const float* ff1_b = (const float*)d_in[10];
  const float* ff2_w = (const float*)d_in[11];
  const float* ff2_b = (const float*)d_in[12];
  const float* ln2_w = (const float*)d_in[13];
  const float* ln2_b = (const float*)d_in[14];
  const float* mus   = (const float*)d_in[15];

  char* ws = (char*)d_ws;
  bf16* region0 = (bf16*)(ws);                         // 512MB: qkv / ffmid
  bf16* xb      = (bf16*)(ws + 536870912L);            // 128MB
  bf16* oproj   = (bf16*)(ws + 671088640L);            // 128MB
  bf16* w_qkv   = (bf16*)(ws + 805306368L);
  bf16* w_out   = (bf16*)(ws + 810024960L);
  bf16* w_ff1   = (bf16*)(ws + 811597824L);
  bf16* w_ff2   = (bf16*)(ws + 817889280L);
  bf16* mubf    = (bf16*)(ws + 824180736L);
  float* munorm = (float*)(ws + 824213504L);
  float* logza  = (float*)(ws);                        // aliases region0

  float* out_f = (float*)d_out;
  float* cp    = out_f;
  float* emb   = out_f + 4194304L;
  float* o_pi  = out_f + 71303168L;
  float* o_A   = out_f + 71303200L;
  float* o_ent = out_f + 71304224L;

  k_f2bf<<<8192, 256, 0, stream>>>(in_series, xb, 67108864L);
  k_f2bf<<<1024, 256, 0, stream>>>(qkv_w, w_qkv, 2359296L);
  k_f2bf<<<1024, 256, 0, stream>>>(out_w, w_out, 786432L);
  k_f2bf<<<1024, 256, 0, stream>>>(ff1_w, w_ff1, 3145728L);
  k_f2bf<<<1024, 256, 0, stream>>>(ff2_w, w_ff2, 3145728L);
  k_mu<<<32, 256, 0, stream>>>(mus, mubf, munorm);

  for (int l = 0; l < 3; l++){
    // qkv = x @ qkv_w^T + b   -> region0 [131072][1536]
    gemm256<0><<<3072, 512, 0, stream>>>(xb, 512, w_qkv + (long)l * 786432L,
                                         qkv_b + (long)l * 1536, region0, 512, 6);
    attention<<<16384, 256, 0, stream>>>(region0);
    // o @ out_w^T + b -> oproj
    gemm256<0><<<1024, 512, 0, stream>>>(region0, 1536, w_out + (long)l * 262144L,
                                         out_b + (long)l * 512, oproj, 512, 2);
    resid_ln<<<131072, 256, 0, stream>>>(xb, oproj, ln1_w + (long)l * 512, ln1_b + (long)l * 512, xb);
    // ffmid = relu(x @ ff1_w^T + b) -> region0 [131072][2048]
    gemm256<1><<<4096, 512, 0, stream>>>(xb, 512, w_ff1 + (long)l * 1048576L,
                                         ff1_b + (long)l * 2048, region0, 512, 8);
    // ffout = ffmid @ ff2_w^T + b -> oproj
    gemm256<0><<<1024, 512, 0, stream>>>(region0, 2048, w_ff2 + (long)l * 1048576L,
                                         ff2_b + (long)l * 512, oproj, 2048, 2);
    resid_ln<<<131072, 256, 0, stream>>>(xb, oproj, ln2_w + (long)l * 512, ln2_b + (long)l * 512, xb);
  }

  k_bf2f<<<8192, 256, 0, stream>>>(xb, emb, 67108864L);
  cluster_logza<<<8192, 256, 0, stream>>>(xb, mubf, munorm, logza);
  hipMemsetAsync(o_ent, 0, 4, stream);
  k_hmm<<<256, 256, 0, stream>>>(logza, pi, Amat, cp, o_ent);
  hipMemcpyAsync(o_pi, pi, 32 * sizeof(float), hipMemcpyDeviceToDevice, stream);
  hipMemcpyAsync(o_A, Amat, 1024 * sizeof(float), hipMemcpyDeviceToDevice, stream);
}

// Round 3
// 4030.863 us; speedup vs baseline: 1.4409x; 1.1994x over previous
//
#include <hip/hip_runtime.h>
#include <stdint.h>

// ---------------------------------------------------------------------------
// TSCluster: 3x TransformerEncoderLayer (post-norm, relu) + cluster softmax +
// sequential HMM recursion.  N*P=131072 tokens, D=512, H=8, DFF=2048, C=32.
// bf16 activations + bf16 MFMA GEMMs (f32 accum), f32 LN/softmax.
// GEMM: 256x256 tile, BK=64, 8 waves, 4-phase/K-tile counted-vmcnt pipeline,
// XOR-swizzled LDS, coalesced epilogue via per-wave LDS roundtrip.
// ---------------------------------------------------------------------------

typedef __bf16 bf16;
typedef __bf16 bf16x2 __attribute__((ext_vector_type(2)));
typedef __bf16 bf16x4 __attribute__((ext_vector_type(4)));
typedef __bf16 bf16x8 __attribute__((ext_vector_type(8)));
typedef float  f32x4  __attribute__((ext_vector_type(4)));
typedef float  f32x2  __attribute__((ext_vector_type(2)));

#define EPSF 1e-10f
#define NROWS 131072L   // N*P

__device__ __forceinline__ float bflo(uint32_t u){ return __uint_as_float(u << 16); }
__device__ __forceinline__ float bfhi(uint32_t u){ return __uint_as_float(u & 0xffff0000u); }

__device__ __forceinline__ void gload_lds16(const bf16* g, bf16* l){
  __builtin_amdgcn_global_load_lds((const __attribute__((address_space(1))) uint32_t*)g,
                                   (__attribute__((address_space(3))) uint32_t*)l,
                                   16, 0, 0);
}

// ---------------------------------------------------------------------------
__global__ void k_f2bf(const float* __restrict__ in, bf16* __restrict__ out, long n){
  const long stride = (long)gridDim.x * blockDim.x * 4;
  for (long i = ((long)blockIdx.x * blockDim.x + threadIdx.x) * 4; i < n; i += stride){
    f32x4 v = *(const f32x4*)(in + i);
    bf16x4 o = { (bf16)v[0], (bf16)v[1], (bf16)v[2], (bf16)v[3] };
    *(bf16x4*)(out + i) = o;
  }
}

// ---------------------------------------------------------------------------
// 256x256x64 8-wave GEMM: C[m,n] = A[m,k] * W[n,k] + bias[n]  (both K-contig)

#define MFMA_PH(RH, CH)                                                       \
  {                                                                           \
    __builtin_amdgcn_s_setprio(1);                                            \
    _Pragma("unroll")                                                         \
    for (int i2 = 0; i2 < 4; i2++) {                                          \
      _Pragma("unroll")                                                       \
      for (int j2 = 0; j2 < 2; j2++) {                                        \
        acc[(RH)*4+i2][(CH)*2+j2] = __builtin_amdgcn_mfma_f32_16x16x32_bf16(  \
            a[i2][0], b[CH][j2][0], acc[(RH)*4+i2][(CH)*2+j2], 0, 0, 0);      \
        acc[(RH)*4+i2][(CH)*2+j2] = __builtin_amdgcn_mfma_f32_16x16x32_bf16(  \
            a[i2][1], b[CH][j2][1], acc[(RH)*4+i2][(CH)*2+j2], 0, 0, 0);      \
      }                                                                       \
    }                                                                         \
    __builtin_amdgcn_s_setprio(0);                                            \
  }

#define RD_A(RH)                                                              \
  _Pragma("unroll")                                                           \
  for (int i2 = 0; i2 < 4; i2++) {                                            \
    a[i2][0] = *(const bf16x8*)&Ac[(aRow + (RH)*64 + i2*16) * 64 + sl0];      \
    a[i2][1] = *(const bf16x8*)&Ac[(aRow + (RH)*64 + i2*16) * 64 + sl1];      \
  }

#define RD_B(CH)                                                              \
  _Pragma("unroll")                                                           \
  for (int j2 = 0; j2 < 2; j2++) {                                            \
    b[CH][j2][0] = *(const bf16x8*)&Bc[(bRow + (CH)*32 + j2*16) * 64 + sl0];  \
    b[CH][j2][1] = *(const bf16x8*)&Bc[(bRow + (CH)*32 + j2*16) * 64 + sl1];  \
  }

#define ISSUE_A(dst, BI, KK) \
  gload_lds16(gA + (long)(BI)*64*lda + (KK), (dst) + (BI)*4096 + wslice)
#define ISSUE_B(dst, BI, KK) \
  gload_lds16(gB + (long)(BI)*64*K   + (KK), (dst) + (BI)*4096 + wslice)

#define WAITV(N)  asm volatile("s_waitcnt vmcnt(" #N ")" ::: "memory")
#define WAITL0    asm volatile("s_waitcnt lgkmcnt(0)" ::: "memory")
#define BARRIER   { __builtin_amdgcn_s_barrier(); asm volatile("" ::: "memory"); }

template<int RELU>
__global__ __launch_bounds__(512, 2)
void gemm256(const bf16* __restrict__ A, long lda,
             const bf16* __restrict__ W,
             const float* __restrict__ bias,
             bf16* __restrict__ Cb, long K, int nbx)
{
  const int tid  = threadIdx.x;
  const int wid  = tid >> 6;
  const int lane = tid & 63;
  const int wr = wid >> 2, wc = wid & 3;
  const long ldc = (long)nbx * 256;

  // XCD-chunked block swizzle (nwg % 8 == 0 for all our shapes)
  const unsigned nwg = gridDim.x;
  const unsigned q   = nwg >> 3;
  const unsigned swz = (blockIdx.x & 7) * q + (blockIdx.x >> 3);
  const unsigned bx  = swz % (unsigned)nbx;
  const unsigned by  = swz / (unsigned)nbx;
  const long bm = (long)by * 256;
  const long bn = (long)bx * 256;

  __shared__ __align__(16) bf16 smem[65536];   // 128 KiB
  bf16* const As0 = smem;
  bf16* const Bs0 = smem + 16384;
  bf16* const As1 = smem + 32768;
  bf16* const Bs1 = smem + 49152;

  const int srow   = wid * 8 + (lane >> 3);
  const int scol   = ((lane & 7) ^ ((lane >> 3) & 7)) * 8;   // inverse swizzle
  const int wslice = wid * 512;
  const bf16* gA = A + (bm + srow) * lda + scol;
  const bf16* gB = W + (bn + srow) * K   + scol;

  const int fr = lane & 15, fg = lane >> 4;
  const int aRow = wr * 128 + fr;
  const int bRow = wc * 64  + fr;
  const int sl0 = ((0 + fg) ^ (fr & 7)) * 8;
  const int sl1 = ((4 + fg) ^ (fr & 7)) * 8;

  f32x4 acc[8][4];
#pragma unroll
  for (int i = 0; i < 8; i++)
#pragma unroll
    for (int j = 0; j < 4; j++) acc[i][j] = (f32x4){0.f, 0.f, 0.f, 0.f};

  bf16x8 a[4][2];
  bf16x8 b[2][2][2];

  const int nt = (int)(K >> 6);

  // ---- prologue: stage tile 0 ----
  ISSUE_A(As0, 0, 0); ISSUE_A(As0, 2, 0);
  ISSUE_B(Bs0, 0, 0); ISSUE_B(Bs0, 1, 0);
  ISSUE_B(Bs0, 2, 0); ISSUE_B(Bs0, 3, 0);
  ISSUE_A(As0, 1, 0); ISSUE_A(As0, 3, 0);
  WAITV(2);
  BARRIER;

  for (int t = 0; t < nt; t++){
    bf16* const Ac = (t & 1) ? As1 : As0;
    bf16* const Bc = (t & 1) ? Bs1 : Bs0;
    bf16* const An = (t & 1) ? As0 : As1;
    bf16* const Bn = (t & 1) ? Bs0 : Bs1;
    const bool stage = (t + 1 < nt);
    const long kn = (long)(t + 1) << 6;

    // ---- phase 0 ----
    RD_A(0); RD_B(0);
    if (stage){ ISSUE_A(An, 0, kn); ISSUE_A(An, 2, kn);
                ISSUE_B(Bn, 0, kn); ISSUE_B(Bn, 1, kn); }
    BARRIER;
    WAITL0;
    MFMA_PH(0, 0);
    BARRIER;

    // ---- phase 1 ----
    RD_B(1);
    if (stage){ ISSUE_B(Bn, 2, kn); ISSUE_B(Bn, 3, kn); WAITV(6); }
    else      { WAITV(0); }
    BARRIER;
    WAITL0;
    MFMA_PH(0, 1);
    BARRIER;

    // ---- phase 2 ----
    RD_A(1);
    if (stage){ ISSUE_A(An, 1, kn); ISSUE_A(An, 3, kn); }
    BARRIER;
    WAITL0;
    MFMA_PH(1, 0);
    BARRIER;

    // ---- phase 3 ----
    WAITV(2);
    BARRIER;
    MFMA_PH(1, 1);
    BARRIER;
  }

  // ---- epilogue: coalesced C-write via per-wave LDS roundtrip ----
  // wave slice: [32][68] f32 (8704 B), pad 68 -> 2-way write alias (free),
  // b128 readback uniform 8 words/bank (conflict-free minimum).
  float* const cw = (float*)smem + wid * 2176;
  const long strip_row0 = bm + wr * 128;
  const long strip_col0 = bn + wc * 64;
  float bv[4];
#pragma unroll
  for (int j = 0; j < 4; j++) bv[j] = bias[strip_col0 + j * 16 + fr];
  const int rrow = lane >> 3;
  const int rcol = (lane & 7) * 8;

#pragma unroll
  for (int ch = 0; ch < 4; ch++){     // 32-row chunks of the 128x64 strip
#pragma unroll
    for (int i2 = 0; i2 < 2; i2++){
      const int i = ch * 2 + i2;
#pragma unroll
      for (int j = 0; j < 4; j++){
#pragma unroll
        for (int r = 0; r < 4; r++){
          float v = acc[i][j][r] + bv[j];
          if (RELU) v = fmaxf(v, 0.f);
          cw[(i2 * 16 + fg * 4 + r) * 68 + j * 16 + fr] = v;
        }
      }
    }
    WAITL0;   // wave-local: writes visible to own lanes' reads
#pragma unroll
    for (int p = 0; p < 4; p++){
      const int row = p * 8 + rrow;
      f32x4 v0 = *(const f32x4*)&cw[row * 68 + rcol];
      f32x4 v1 = *(const f32x4*)&cw[row * 68 + rcol + 4];
      bf16x8 o = { (bf16)v0[0], (bf16)v0[1], (bf16)v0[2], (bf16)v0[3],
                   (bf16)v1[0], (bf16)v1[1], (bf16)v1[2], (bf16)v1[3] };
      *(bf16x8*)&Cb[(strip_row0 + ch * 32 + row) * ldc + strip_col0 + rcol] = o;
    }
    WAITL0;   // reads done before next chunk overwrites the slice
  }
}

// ---------------------------------------------------------------------------
// Fused attention for one (n, h): Q,K,V are 64x64 bf16 slices of the qkv buffer
// [NROWS][1536].  O overwrites the Q slice.  scale = 1/sqrt(64) = 0.125.
__global__ __launch_bounds__(256)
void attention(bf16* __restrict__ qkv)
{
  const int blk = blockIdx.x;
  const long n = blk >> 3;
  const int h  = blk & 7;
  const int tid = threadIdx.x;
  const int wid = tid >> 6, lane = tid & 63;

  __shared__ __align__(16) bf16 Qs[64][72];
  __shared__ __align__(16) bf16 Ks[64][72];
  __shared__ __align__(16) bf16 Vt[64][72];

  bf16* base = qkv + n * 64 * 1536 + h * 64;

  for (int c = tid; c < 512; c += 256){
    const int row = c >> 3, col = (c & 7) * 8;
    const long go = (long)row * 1536 + col;
    *(bf16x8*)&Qs[row][col] = *(const bf16x8*)(base + go);
    *(bf16x8*)&Ks[row][col] = *(const bf16x8*)(base + 512 + go);
    bf16x8 v = *(const bf16x8*)(base + 1024 + go);
#pragma unroll
    for (int e = 0; e < 8; e++) Vt[col + e][row] = v[e];
  }
  __syncthreads();

  const int fr = lane & 15, fg = lane >> 4;
  f32x4 sacc[4];
#pragma unroll
  for (int j = 0; j < 4; j++) sacc[j] = (f32x4){0.f, 0.f, 0.f, 0.f};
#pragma unroll
  for (int ks = 0; ks < 2; ks++){
    bf16x8 aa = *(const bf16x8*)&Qs[wid * 16 + fr][ks * 32 + fg * 8];
#pragma unroll
    for (int j = 0; j < 4; j++){
      bf16x8 bb = *(const bf16x8*)&Ks[j * 16 + fr][ks * 32 + fg * 8];
      sacc[j] = __builtin_amdgcn_mfma_f32_16x16x32_bf16(aa, bb, sacc[j], 0, 0, 0);
    }
  }

  float pv[4][4];
#pragma unroll
  for (int r = 0; r < 4; r++){
    float m = -1e30f;
#pragma unroll
    for (int j = 0; j < 4; j++) m = fmaxf(m, sacc[j][r]);
#pragma unroll
    for (int msk = 1; msk < 16; msk <<= 1) m = fmaxf(m, __shfl_xor(m, msk));
    float s = 0.f;
#pragma unroll
    for (int j = 0; j < 4; j++){
      float p = __expf((sacc[j][r] - m) * 0.125f);
      pv[j][r] = p; s += p;
    }
#pragma unroll
    for (int msk = 1; msk < 16; msk <<= 1) s += __shfl_xor(s, msk);
    const float inv = 1.f / s;
#pragma unroll
    for (int j = 0; j < 4; j++) pv[j][r] *= inv;
  }

#pragma unroll
  for (int j = 0; j < 4; j++)
#pragma unroll
    for (int r = 0; r < 4; r++)
      Qs[wid * 16 + fg * 4 + r][j * 16 + fr] = (bf16)pv[j][r];
  __syncthreads();

  f32x4 oacc[4];
#pragma unroll
  for (int j = 0; j < 4; j++) oacc[j] = (f32x4){0.f, 0.f, 0.f, 0.f};
#pragma unroll
  for (int ks = 0; ks < 2; ks++){
    bf16x8 aa = *(const bf16x8*)&Qs[wid * 16 + fr][ks * 32 + fg * 8];
#pragma unroll
    for (int j = 0; j < 4; j++){
      bf16x8 bb = *(const bf16x8*)&Vt[j * 16 + fr][ks * 32 + fg * 8];
      oacc[j] = __builtin_amdgcn_mfma_f32_16x16x32_bf16(aa, bb, oacc[j], 0, 0, 0);
    }
  }
#pragma unroll
  for (int j = 0; j < 4; j++)
#pragma unroll
    for (int r = 0; r < 4; r++)
      base[(long)(wid * 16 + fg * 4 + r) * 1536 + j * 16 + fr] = (bf16)oacc[j][r];
}

// ---------------------------------------------------------------------------
// y = LayerNorm(x + o) * w + b ; one WAVE per row, 4 rows/block, no LDS.
// Optionally also writes the f32 result to EF (fused emb_ts output).
__global__ __launch_bounds__(256)
void resid_ln(const bf16* __restrict__ X, const bf16* __restrict__ O,
              const float* __restrict__ w, const float* __restrict__ b,
              bf16* __restrict__ Y, float* __restrict__ EF)
{
  const int wid = threadIdx.x >> 6, lane = threadIdx.x & 63;
  const long row = (long)blockIdx.x * 4 + wid;
  const uint4 xu = ((const uint4*)(X + row * 512))[lane];
  const uint4 ou = ((const uint4*)(O + row * 512))[lane];
  float s[8];
  s[0] = bflo(xu.x) + bflo(ou.x);  s[1] = bfhi(xu.x) + bfhi(ou.x);
  s[2] = bflo(xu.y) + bflo(ou.y);  s[3] = bfhi(xu.y) + bfhi(ou.y);
  s[4] = bflo(xu.z) + bflo(ou.z);  s[5] = bfhi(xu.z) + bfhi(ou.z);
  s[6] = bflo(xu.w) + bflo(ou.w);  s[7] = bfhi(xu.w) + bfhi(ou.w);
  float sum = 0.f, sq = 0.f;
#pragma unroll
  for (int e = 0; e < 8; e++){ sum += s[e]; sq += s[e] * s[e]; }
#pragma unroll
  for (int m = 1; m < 64; m <<= 1){ sum += __shfl_xor(sum, m); sq += __shfl_xor(sq, m); }
  const float mean = sum * (1.f / 512.f);
  const float var  = sq * (1.f / 512.f) - mean * mean;
  const float rs   = rsqrtf(var + 1e-5f);
  const f32x4 w0 = *(const f32x4*)(w + 8 * lane);
  const f32x4 w1 = *(const f32x4*)(w + 8 * lane + 4);
  const f32x4 b0 = *(const f32x4*)(b + 8 * lane);
  const f32x4 b1 = *(const f32x4*)(b + 8 * lane + 4);
  float o[8];
#pragma unroll
  for (int e = 0; e < 4; e++) o[e]     = (s[e]     - mean) * rs * w0[e] + b0[e];
#pragma unroll
  for (int e = 0; e < 4; e++) o[e + 4] = (s[e + 4] - mean) * rs * w1[e] + b1[e];
  bf16x8 ov = { (bf16)o[0], (bf16)o[1], (bf16)o[2], (bf16)o[3],
                (bf16)o[4], (bf16)o[5], (bf16)o[6], (bf16)o[7] };
  *(bf16x8*)(Y + row * 512 + 8 * lane) = ov;
  if (EF){
    f32x4 e0 = { o[0], o[1], o[2], o[3] };
    f32x4 e1 = { o[4], o[5], o[6], o[7] };
    *(f32x4*)(EF + row * 512 + 8 * lane) = e0;
    *(f32x4*)(EF + row * 512 + 8 * lane + 4) = e1;
  }
}

// ---------------------------------------------------------------------------
__global__ __launch_bounds__(256)
void k_mu(const float* __restrict__ mus, bf16* __restrict__ mubf, float* __restrict__ munorm)
{
  const int c = blockIdx.x, tid = threadIdx.x, lane = tid & 63, wid = tid >> 6;
  const f32x2 v = *(const f32x2*)(mus + c * 512 + 2 * tid);
  const float t0 = tanhf(v[0]), t1 = tanhf(v[1]);
  bf16x2 o2 = { (bf16)t0, (bf16)t1 };
  *(bf16x2*)(mubf + c * 512 + 2 * tid) = o2;
  float sq = t0 * t0 + t1 * t1;
#pragma unroll
  for (int m = 1; m < 64; m <<= 1) sq += __shfl_xor(sq, m);
  __shared__ float red[4];
  if (lane == 0) red[wid] = sq;
  __syncthreads();
  if (tid == 0) munorm[c] = red[0] + red[1] + red[2] + red[3];
}

// ---------------------------------------------------------------------------
__global__ __launch_bounds__(256)
void cluster_logza(const bf16* __restrict__ X, const bf16* __restrict__ MU,
                   const float* __restrict__ munorm, float* __restrict__ out)
{
  const int tid = threadIdx.x, lane = tid & 63, wid = tid >> 6;
  __shared__ __align__(16) bf16 mus[32][512];
  __shared__ float xs[512];
  __shared__ float red[4];
  __shared__ float dots[32];
  for (int c = tid; c < 2048; c += 256){
    const int r = c >> 6, col = (c & 63) * 8;
    *(bf16x8*)&mus[r][col] = *(const bf16x8*)(MU + r * 512 + col);
  }
  const int cc = tid >> 3, seg = tid & 7;
  const long row0 = (long)blockIdx.x * 16;
  __syncthreads();
  for (int rr = 0; rr < 16; rr++){
    const long row = row0 + rr;
    const uint32_t u = ((const uint32_t*)(X + row * 512))[tid];
    const float aa = bflo(u), bb = bfhi(u);
    xs[2 * tid] = aa; xs[2 * tid + 1] = bb;
    float sq = aa * aa + bb * bb;
#pragma unroll
    for (int m = 1; m < 64; m <<= 1) sq += __shfl_xor(sq, m);
    if (lane == 0) red[wid] = sq;
    __syncthreads();
    const float xn = red[0] + red[1] + red[2] + red[3];
    float p = 0.f;
#pragma unroll
    for (int jj = 0; jj < 8; jj++){
      const int col = jj * 64 + seg * 8;
      bf16x8 m8 = *(const bf16x8*)&mus[cc][col];
      const float* xv = &xs[col];
#pragma unroll
      for (int e = 0; e < 8; e++) p += xv[e] * (float)m8[e];
    }
#pragma unroll
    for (int m = 1; m < 8; m <<= 1) p += __shfl_xor(p, m);
    if (seg == 0) dots[cc] = p;
    __syncthreads();
    if (tid < 32){
      const float dist = xn + munorm[tid] - 2.f * dots[tid];
      const float lg = -dist * 0.1f;
      float mx = lg;
#pragma unroll
      for (int m = 1; m < 32; m <<= 1) mx = fmaxf(mx, __shfl_xor(mx, m, 32));
      const float z = __expf(lg - mx);
      float s = z;
#pragma unroll
      for (int m = 1; m < 32; m <<= 1) s += __shfl_xor(s, m, 32);
      out[row * 32 + tid] = logf(z / s + EPSF);
    }
    __syncthreads();
  }
}

// ---------------------------------------------------------------------------
__global__ __launch_bounds__(256)
void k_hmm(const float* __restrict__ lza, const float* __restrict__ pi,
           const float* __restrict__ A, float* __restrict__ cp, float* __restrict__ ent)
{
  __shared__ float As[32][33];
  const int tid = threadIdx.x;
  for (int i = tid; i < 1024; i += 256) As[i >> 5][i & 31] = A[i];
  __syncthreads();
  const int j = tid & 31;
  const long n = (long)blockIdx.x * 8 + (tid >> 5);
  const float* lz = lza + n * 2048;

  float c = logf(pi[j] + EPSF) + lz[j];
  {
    float mx = c;
#pragma unroll
    for (int m = 1; m < 32; m <<= 1) mx = fmaxf(mx, __shfl_xor(mx, m, 32));
    float z = __expf(c - mx), s = z;
#pragma unroll
    for (int m = 1; m < 32; m <<= 1) s += __shfl_xor(s, m, 32);
    c = z / s;
  }
  cp[n * 2048 + j] = c;
  float ea = -c * logf(c + EPSF);

  for (int p = 1; p < 64; p++){
    float y = 0.f;
#pragma unroll
    for (int i = 0; i < 32; i++) y += __shfl(c, i, 32) * As[i][j];
    float t = logf(y + EPSF) + lz[p * 32 + j];
    float mx = t;
#pragma unroll
    for (int m = 1; m < 32; m <<= 1) mx = fmaxf(mx, __shfl_xor(mx, m, 32));
    float z = __expf(t - mx), s = z;
#pragma unroll
    for (int m = 1; m < 32; m <<= 1) s += __shfl_xor(s, m, 32);
    c = z / s;
    cp[n * 2048 + p * 32 + j] = c;
    ea += -c * logf(c + EPSF);
  }
#pragma unroll
  for (int m = 1; m < 32; m <<= 1) ea += __shfl_xor(ea, m, 32);
  if (j == 0) atomicAdd(ent, ea * (1.f / 131072.f));
}

// ---------------------------------------------------------------------------
extern "C" void kernel_launch(void* const* d_in, const int* in_sizes, int n_in,
                              void* d_out, int out_size, void* d_ws, size_t ws_size,
                              hipStream_t stream)
{
  (void)in_sizes; (void)n_in; (void)out_size; (void)ws_size;
  const float* in_series = (const float*)d_in[0];
  const float* pi    = (const float*)d_in[1];
  const float* Amat  = (const float*)d_in[2];
  const float* qkv_w = (const float*)d_in[3];
  const float* qkv_b = (const float*)d_in[4];
  const float* out_w = (const float*)d_in[5];
  const float* out_b = (const float*)d_in[6];
  const float* ln1_w = (const float*)d_in[7];
  const float* ln1_b = (const float*)d_in[8];
  const float* ff1_w = (const float*)d_in[9];
  const float* ff1_b = (const float*)d_in[10];
  const float* ff2_w = (const float*)d_in[11];
  const float* ff2_b = (const float*)d_in[12];
  const float* ln2_w = (const float*)d_in[13];
  const float* ln2_b = (const float*)d_in[14];
  const float* mus   = (const float*)d_in[15];

  char* ws = (char*)d_ws;
  bf16* region0 = (bf16*)(ws);                         // 512MB: qkv / ffmid
  bf16* xb      = (bf16*)(ws + 536870912L);            // 128MB
  bf16* oproj   = (bf16*)(ws + 671088640L);            // 128MB
  bf16* w_qkv   = (bf16*)(ws + 805306368L);
  bf16* w_out   = (bf16*)(ws + 810024960L);
  bf16* w_ff1   = (bf16*)(ws + 811597824L);
  bf16* w_ff2   = (bf16*)(ws + 817889280L);
  bf16* mubf    = (bf16*)(ws + 824180736L);
  float* munorm = (float*)(ws + 824213504L);
  float* logza  = (float*)(ws);                        // aliases region0

  float* out_f = (float*)d_out;
  float* cp    = out_f;
  float* emb   = out_f + 4194304L;
  float* o_pi  = out_f + 71303168L;
  float* o_A   = out_f + 71303200L;
  float* o_ent = out_f + 71304224L;

  k_f2bf<<<8192, 256, 0, stream>>>(in_series, xb, 67108864L);
  k_f2bf<<<1024, 256, 0, stream>>>(qkv_w, w_qkv, 2359296L);
  k_f2bf<<<1024, 256, 0, stream>>>(out_w, w_out, 786432L);
  k_f2bf<<<1024, 256, 0, stream>>>(ff1_w, w_ff1, 3145728L);
  k_f2bf<<<1024, 256, 0, stream>>>(ff2_w, w_ff2, 3145728L);
  k_mu<<<32, 256, 0, stream>>>(mus, mubf, munorm);

  for (int l = 0; l < 3; l++){
    // qkv = x @ qkv_w^T + b   -> region0 [131072][1536]
    gemm256<0><<<3072, 512, 0, stream>>>(xb, 512, w_qkv + (long)l * 786432L,
                                         qkv_b + (long)l * 1536, region0, 512, 6);
    attention<<<16384, 256, 0, stream>>>(region0);
    // o @ out_w^T + b -> oproj
    gemm256<0><<<1024, 512, 0, stream>>>(region0, 1536, w_out + (long)l * 262144L,
                                         out_b + (long)l * 512, oproj, 512, 2);
    resid_ln<<<32768, 256, 0, stream>>>(xb, oproj, ln1_w + (long)l * 512,
                                        ln1_b + (long)l * 512, xb, nullptr);
    // ffmid = relu(x @ ff1_w^T + b) -> region0 [131072][2048]
    gemm256<1><<<4096, 512, 0, stream>>>(xb, 512, w_ff1 + (long)l * 1048576L,
                                         ff1_b + (long)l * 2048, region0, 512, 8);
    // ffout = ffmid @ ff2_w^T + b -> oproj
    gemm256<0><<<1024, 512, 0, stream>>>(region0, 2048, w_ff2 + (long)l * 1048576L,
                                         ff2_b + (long)l * 512, oproj, 2048, 2);
    // last layer: fuse f32 emb_ts output into the LN
    resid_ln<<<32768, 256, 0, stream>>>(xb, oproj, ln2_w + (long)l * 512,
                                        ln2_b + (long)l * 512, xb,
                                        (l == 2) ? emb : nullptr);
  }

  cluster_logza<<<8192, 256, 0, stream>>>(xb, mubf, munorm, logza);
  hipMemsetAsync(o_ent, 0, 4, stream);
  k_hmm<<<256, 256, 0, stream>>>(logza, pi, Amat, cp, o_ent);
  hipMemcpyAsync(o_pi, pi, 32 * sizeof(float), hipMemcpyDeviceToDevice, stream);
  hipMemcpyAsync(o_A, Amat, 1024 * sizeof(float), hipMemcpyDeviceToDevice, stream);
}

// Round 4
// 3963.013 us; speedup vs baseline: 1.4656x; 1.0171x over previous
//
#include <hip/hip_runtime.h>
#include <stdint.h>

// ---------------------------------------------------------------------------
// TSCluster: 3x TransformerEncoderLayer (post-norm, relu) + cluster softmax +
// sequential HMM recursion.  N*P=131072 tokens, D=512, H=8, DFF=2048, C=32.
// bf16 activations + bf16 MFMA GEMMs (f32 accum), f32 LN/softmax.
// GEMM: 256x256 tile, BK=64, 8 waves, 2-phase/K-tile, ONE barrier per phase,
// counted vmcnt (6/2), XOR-swizzled LDS, bf16-LDS coalesced epilogue.
// ---------------------------------------------------------------------------

typedef __bf16 bf16;
typedef __bf16 bf16x2 __attribute__((ext_vector_type(2)));
typedef __bf16 bf16x4 __attribute__((ext_vector_type(4)));
typedef __bf16 bf16x8 __attribute__((ext_vector_type(8)));
typedef float  f32x4  __attribute__((ext_vector_type(4)));
typedef float  f32x2  __attribute__((ext_vector_type(2)));

#define EPSF 1e-10f
#define NROWS 131072L   // N*P

__device__ __forceinline__ float bflo(uint32_t u){ return __uint_as_float(u << 16); }
__device__ __forceinline__ float bfhi(uint32_t u){ return __uint_as_float(u & 0xffff0000u); }

__device__ __forceinline__ void gload_lds16(const bf16* g, bf16* l){
  __builtin_amdgcn_global_load_lds((const __attribute__((address_space(1))) uint32_t*)g,
                                   (__attribute__((address_space(3))) uint32_t*)l,
                                   16, 0, 0);
}

// ---------------------------------------------------------------------------
__global__ void k_f2bf(const float* __restrict__ in, bf16* __restrict__ out, long n){
  const long stride = (long)gridDim.x * blockDim.x * 4;
  for (long i = ((long)blockIdx.x * blockDim.x + threadIdx.x) * 4; i < n; i += stride){
    f32x4 v = *(const f32x4*)(in + i);
    bf16x4 o = { (bf16)v[0], (bf16)v[1], (bf16)v[2], (bf16)v[3] };
    *(bf16x4*)(out + i) = o;
  }
}

// ---------------------------------------------------------------------------
// 256x256x64 8-wave GEMM: C[m,n] = A[m,k] * W[n,k] + bias[n]  (both K-contig)

#define MFMA_HALF(RH)                                                         \
  {                                                                           \
    __builtin_amdgcn_s_setprio(1);                                            \
    _Pragma("unroll")                                                         \
    for (int kk = 0; kk < 2; kk++) {                                          \
      _Pragma("unroll")                                                       \
      for (int i2 = 0; i2 < 4; i2++) {                                        \
        _Pragma("unroll")                                                     \
        for (int jj = 0; jj < 4; jj++) {                                      \
          acc[(RH)*4+i2][jj] = __builtin_amdgcn_mfma_f32_16x16x32_bf16(       \
              a[i2][kk], b[jj][kk], acc[(RH)*4+i2][jj], 0, 0, 0);             \
        }                                                                     \
      }                                                                       \
    }                                                                         \
    __builtin_amdgcn_s_setprio(0);                                            \
  }

#define RD_A(RH)                                                              \
  _Pragma("unroll")                                                           \
  for (int i2 = 0; i2 < 4; i2++) {                                            \
    a[i2][0] = *(const bf16x8*)&Ac[(aRow + (RH)*64 + i2*16) * 64 + sl0];      \
    a[i2][1] = *(const bf16x8*)&Ac[(aRow + (RH)*64 + i2*16) * 64 + sl1];      \
  }

#define RD_B_ALL                                                              \
  _Pragma("unroll")                                                           \
  for (int jj = 0; jj < 4; jj++) {                                            \
    b[jj][0] = *(const bf16x8*)&Bc[(bRow + jj*16) * 64 + sl0];                \
    b[jj][1] = *(const bf16x8*)&Bc[(bRow + jj*16) * 64 + sl1];                \
  }

#define ISSUE_A(dst, BI, KK) \
  gload_lds16(gA + (long)(BI)*64*lda + (KK), (dst) + (BI)*4096 + wslice)
#define ISSUE_B(dst, BI, KK) \
  gload_lds16(gB + (long)(BI)*64*K   + (KK), (dst) + (BI)*4096 + wslice)

#define WAITV(N)  asm volatile("s_waitcnt vmcnt(" #N ")" ::: "memory")
#define WAITL0    asm volatile("s_waitcnt lgkmcnt(0)" ::: "memory")
#define BARRIER   { __builtin_amdgcn_s_barrier(); asm volatile("" ::: "memory"); }

template<int RELU>
__global__ __launch_bounds__(512, 2)
void gemm256(const bf16* __restrict__ A, long lda,
             const bf16* __restrict__ W,
             const float* __restrict__ bias,
             bf16* __restrict__ Cb, long K, int nbx)
{
  const int tid  = threadIdx.x;
  const int wid  = tid >> 6;
  const int lane = tid & 63;
  const int wr = wid >> 2, wc = wid & 3;
  const long ldc = (long)nbx * 256;

  // XCD-chunked block swizzle (nwg % 8 == 0 for all our shapes)
  const unsigned nwg = gridDim.x;
  const unsigned q   = nwg >> 3;
  const unsigned swz = (blockIdx.x & 7) * q + (blockIdx.x >> 3);
  const unsigned bx  = swz % (unsigned)nbx;
  const unsigned by  = swz / (unsigned)nbx;
  const long bm = (long)by * 256;
  const long bn = (long)bx * 256;

  __shared__ __align__(16) bf16 smem[65536];   // 128 KiB
  bf16* const As0 = smem;
  bf16* const Bs0 = smem + 16384;
  bf16* const As1 = smem + 32768;
  bf16* const Bs1 = smem + 49152;

  const int srow   = wid * 8 + (lane >> 3);
  const int scol   = ((lane & 7) ^ ((lane >> 3) & 7)) * 8;   // inverse swizzle
  const int wslice = wid * 512;
  const bf16* gA = A + (bm + srow) * lda + scol;
  const bf16* gB = W + (bn + srow) * K   + scol;

  const int fr = lane & 15, fg = lane >> 4;
  const int aRow = wr * 128 + fr;
  const int bRow = wc * 64  + fr;
  const int sl0 = ((0 + fg) ^ (fr & 7)) * 8;
  const int sl1 = ((4 + fg) ^ (fr & 7)) * 8;

  f32x4 acc[8][4];
#pragma unroll
  for (int i = 0; i < 8; i++)
#pragma unroll
    for (int j = 0; j < 4; j++) acc[i][j] = (f32x4){0.f, 0.f, 0.f, 0.f};

  bf16x8 a[4][2];
  bf16x8 b[4][2];

  const int nt = (int)(K >> 6);

  // ---- prologue: stage tile 0; group1 = {B0..B3,A0,A2}, group2 = {A1,A3} ----
  ISSUE_B(Bs0, 0, 0); ISSUE_B(Bs0, 1, 0); ISSUE_B(Bs0, 2, 0); ISSUE_B(Bs0, 3, 0);
  ISSUE_A(As0, 0, 0); ISSUE_A(As0, 2, 0);
  ISSUE_A(As0, 1, 0); ISSUE_A(As0, 3, 0);
  WAITV(2);          // group1 landed; A1,A3 float
  BARRIER;

  for (int t = 0; t < nt; t++){
    bf16* const Ac = (t & 1) ? As1 : As0;
    bf16* const Bc = (t & 1) ? Bs1 : Bs0;
    bf16* const An = (t & 1) ? As0 : As1;
    bf16* const Bn = (t & 1) ? Bs0 : Bs1;
    const bool stage = (t + 1 < nt);
    const long kn = (long)(t + 1) << 6;

    // ---- phase 0: A rows half-0, all B cols ----
    RD_A(0); RD_B_ALL;
    if (stage){ ISSUE_B(Bn, 0, kn); ISSUE_B(Bn, 1, kn);
                ISSUE_B(Bn, 2, kn); ISSUE_B(Bn, 3, kn);
                ISSUE_A(An, 0, kn); ISSUE_A(An, 2, kn); }
    WAITL0;
    MFMA_HALF(0);
    if (stage){ WAITV(6); } else { WAITV(0); }   // A1,A3 of t landed (P1 readers)
    BARRIER;

    // ---- phase 1: A rows half-1 ----
    RD_A(1);
    if (stage){ ISSUE_A(An, 1, kn); ISSUE_A(An, 3, kn); }
    WAITL0;
    MFMA_HALF(1);
    if (stage){ WAITV(2); }                      // group1 of t+1 landed (next P0)
    BARRIER;
  }

  // ---- epilogue: coalesced C-write via per-wave bf16 LDS roundtrip ----
  // wave slice [32][72] bf16 (4608 B); b128 readback at row stride 144B.
  bf16* const cw = smem + wid * 2304;
  const long strip_row0 = bm + wr * 128;
  const long strip_col0 = bn + wc * 64;
  float bv[4];
#pragma unroll
  for (int j = 0; j < 4; j++) bv[j] = bias[strip_col0 + j * 16 + fr];
  const int rrow = lane >> 3;
  const int rcol = (lane & 7) * 8;

#pragma unroll
  for (int ch = 0; ch < 4; ch++){     // 32-row chunks of the 128x64 strip
#pragma unroll
    for (int i2 = 0; i2 < 2; i2++){
      const int i = ch * 2 + i2;
#pragma unroll
      for (int j = 0; j < 4; j++){
#pragma unroll
        for (int r = 0; r < 4; r++){
          float v = acc[i][j][r] + bv[j];
          if (RELU) v = fmaxf(v, 0.f);
          cw[(i2 * 16 + fg * 4 + r) * 72 + j * 16 + fr] = (bf16)v;
        }
      }
    }
    WAITL0;   // wave-local: ds_writes visible to own lanes' reads
#pragma unroll
    for (int p = 0; p < 4; p++){
      const int row = p * 8 + rrow;
      bf16x8 o = *(const bf16x8*)&cw[row * 72 + rcol];
      *(bf16x8*)&Cb[(strip_row0 + ch * 32 + row) * ldc + strip_col0 + rcol] = o;
    }
    WAITL0;   // reads done before next chunk overwrites the slice
  }
}

// ---------------------------------------------------------------------------
// Fused attention for one (n, h): Q,K,V are 64x64 bf16 slices of the qkv buffer
// [NROWS][1536].  O overwrites the Q slice.  scale = 1/sqrt(64) = 0.125.
__global__ __launch_bounds__(256)
void attention(bf16* __restrict__ qkv)
{
  const int blk = blockIdx.x;
  const long n = blk >> 3;
  const int h  = blk & 7;
  const int tid = threadIdx.x;
  const int wid = tid >> 6, lane = tid & 63;

  __shared__ __align__(16) bf16 Qs[64][72];
  __shared__ __align__(16) bf16 Ks[64][72];
  __shared__ __align__(16) bf16 Vt[64][72];

  bf16* base = qkv + n * 64 * 1536 + h * 64;

  for (int c = tid; c < 512; c += 256){
    const int row = c >> 3, col = (c & 7) * 8;
    const long go = (long)row * 1536 + col;
    *(bf16x8*)&Qs[row][col] = *(const bf16x8*)(base + go);
    *(bf16x8*)&Ks[row][col] = *(const bf16x8*)(base + 512 + go);
    bf16x8 v = *(const bf16x8*)(base + 1024 + go);
#pragma unroll
    for (int e = 0; e < 8; e++) Vt[col + e][row] = v[e];
  }
  __syncthreads();

  const int fr = lane & 15, fg = lane >> 4;
  f32x4 sacc[4];
#pragma unroll
  for (int j = 0; j < 4; j++) sacc[j] = (f32x4){0.f, 0.f, 0.f, 0.f};
#pragma unroll
  for (int ks = 0; ks < 2; ks++){
    bf16x8 aa = *(const bf16x8*)&Qs[wid * 16 + fr][ks * 32 + fg * 8];
#pragma unroll
    for (int j = 0; j < 4; j++){
      bf16x8 bb = *(const bf16x8*)&Ks[j * 16 + fr][ks * 32 + fg * 8];
      sacc[j] = __builtin_amdgcn_mfma_f32_16x16x32_bf16(aa, bb, sacc[j], 0, 0, 0);
    }
  }

  float pv[4][4];
#pragma unroll
  for (int r = 0; r < 4; r++){
    float m = -1e30f;
#pragma unroll
    for (int j = 0; j < 4; j++) m = fmaxf(m, sacc[j][r]);
#pragma unroll
    for (int msk = 1; msk < 16; msk <<= 1) m = fmaxf(m, __shfl_xor(m, msk));
    float s = 0.f;
#pragma unroll
    for (int j = 0; j < 4; j++){
      float p = __expf((sacc[j][r] - m) * 0.125f);
      pv[j][r] = p; s += p;
    }
#pragma unroll
    for (int msk = 1; msk < 16; msk <<= 1) s += __shfl_xor(s, msk);
    const float inv = 1.f / s;
#pragma unroll
    for (int j = 0; j < 4; j++) pv[j][r] *= inv;
  }

#pragma unroll
  for (int j = 0; j < 4; j++)
#pragma unroll
    for (int r = 0; r < 4; r++)
      Qs[wid * 16 + fg * 4 + r][j * 16 + fr] = (bf16)pv[j][r];
  __syncthreads();

  f32x4 oacc[4];
#pragma unroll
  for (int j = 0; j < 4; j++) oacc[j] = (f32x4){0.f, 0.f, 0.f, 0.f};
#pragma unroll
  for (int ks = 0; ks < 2; ks++){
    bf16x8 aa = *(const bf16x8*)&Qs[wid * 16 + fr][ks * 32 + fg * 8];
#pragma unroll
    for (int j = 0; j < 4; j++){
      bf16x8 bb = *(const bf16x8*)&Vt[j * 16 + fr][ks * 32 + fg * 8];
      oacc[j] = __builtin_amdgcn_mfma_f32_16x16x32_bf16(aa, bb, oacc[j], 0, 0, 0);
    }
  }
#pragma unroll
  for (int j = 0; j < 4; j++)
#pragma unroll
    for (int r = 0; r < 4; r++)
      base[(long)(wid * 16 + fg * 4 + r) * 1536 + j * 16 + fr] = (bf16)oacc[j][r];
}

// ---------------------------------------------------------------------------
// y = LayerNorm(x + o) * w + b ; one WAVE per row, 4 rows/block, no LDS.
// Optionally also writes the f32 result to EF (fused emb_ts output).
__global__ __launch_bounds__(256)
void resid_ln(const bf16* __restrict__ X, const bf16* __restrict__ O,
              const float* __restrict__ w, const float* __restrict__ b,
              bf16* __restrict__ Y, float* __restrict__ EF)
{
  const int wid = threadIdx.x >> 6, lane = threadIdx.x & 63;
  const long row = (long)blockIdx.x * 4 + wid;
  const uint4 xu = ((const uint4*)(X + row * 512))[lane];
  const uint4 ou = ((const uint4*)(O + row * 512))[lane];
  float s[8];
  s[0] = bflo(xu.x) + bflo(ou.x);  s[1] = bfhi(xu.x) + bfhi(ou.x);
  s[2] = bflo(xu.y) + bflo(ou.y);  s[3] = bfhi(xu.y) + bfhi(ou.y);
  s[4] = bflo(xu.z) + bflo(ou.z);  s[5] = bfhi(xu.z) + bfhi(ou.z);
  s[6] = bflo(xu.w) + bflo(ou.w);  s[7] = bfhi(xu.w) + bfhi(ou.w);
  float sum = 0.f, sq = 0.f;
#pragma unroll
  for (int e = 0; e < 8; e++){ sum += s[e]; sq += s[e] * s[e]; }
#pragma unroll
  for (int m = 1; m < 64; m <<= 1){ sum += __shfl_xor(sum, m); sq += __shfl_xor(sq, m); }
  const float mean = sum * (1.f / 512.f);
  const float var  = sq * (1.f / 512.f) - mean * mean;
  const float rs   = rsqrtf(var + 1e-5f);
  const f32x4 w0 = *(const f32x4*)(w + 8 * lane);
  const f32x4 w1 = *(const f32x4*)(w + 8 * lane + 4);
  const f32x4 b0 = *(const f32x4*)(b + 8 * lane);
  const f32x4 b1 = *(const f32x4*)(b + 8 * lane + 4);
  float o[8];
#pragma unroll
  for (int e = 0; e < 4; e++) o[e]     = (s[e]     - mean) * rs * w0[e] + b0[e];
#pragma unroll
  for (int e = 0; e < 4; e++) o[e + 4] = (s[e + 4] - mean) * rs * w1[e] + b1[e];
  bf16x8 ov = { (bf16)o[0], (bf16)o[1], (bf16)o[2], (bf16)o[3],
                (bf16)o[4], (bf16)o[5], (bf16)o[6], (bf16)o[7] };
  *(bf16x8*)(Y + row * 512 + 8 * lane) = ov;
  if (EF){
    f32x4 e0 = { o[0], o[1], o[2], o[3] };
    f32x4 e1 = { o[4], o[5], o[6], o[7] };
    *(f32x4*)(EF + row * 512 + 8 * lane) = e0;
    *(f32x4*)(EF + row * 512 + 8 * lane + 4) = e1;
  }
}

// ---------------------------------------------------------------------------
__global__ __launch_bounds__(256)
void k_mu(const float* __restrict__ mus, bf16* __restrict__ mubf, float* __restrict__ munorm)
{
  const int c = blockIdx.x, tid = threadIdx.x, lane = tid & 63, wid = tid >> 6;
  const f32x2 v = *(const f32x2*)(mus + c * 512 + 2 * tid);
  const float t0 = tanhf(v[0]), t1 = tanhf(v[1]);
  bf16x2 o2 = { (bf16)t0, (bf16)t1 };
  *(bf16x2*)(mubf + c * 512 + 2 * tid) = o2;
  float sq = t0 * t0 + t1 * t1;
#pragma unroll
  for (int m = 1; m < 64; m <<= 1) sq += __shfl_xor(sq, m);
  __shared__ float red[4];
  if (lane == 0) red[wid] = sq;
  __syncthreads();
  if (tid == 0) munorm[c] = red[0] + red[1] + red[2] + red[3];
}

// ---------------------------------------------------------------------------
__global__ __launch_bounds__(256)
void cluster_logza(const bf16* __restrict__ X, const bf16* __restrict__ MU,
                   const float* __restrict__ munorm, float* __restrict__ out)
{
  const int tid = threadIdx.x, lane = tid & 63, wid = tid >> 6;
  __shared__ __align__(16) bf16 mus[32][512];
  __shared__ float xs[512];
  __shared__ float red[4];
  __shared__ float dots[32];
  for (int c = tid; c < 2048; c += 256){
    const int r = c >> 6, col = (c & 63) * 8;
    *(bf16x8*)&mus[r][col] = *(const bf16x8*)(MU + r * 512 + col);
  }
  const int cc = tid >> 3, seg = tid & 7;
  const long row0 = (long)blockIdx.x * 16;
  __syncthreads();
  for (int rr = 0; rr < 16; rr++){
    const long row = row0 + rr;
    const uint32_t u = ((const uint32_t*)(X + row * 512))[tid];
    const float aa = bflo(u), bb = bfhi(u);
    xs[2 * tid] = aa; xs[2 * tid + 1] = bb;
    float sq = aa * aa + bb * bb;
#pragma unroll
    for (int m = 1; m < 64; m <<= 1) sq += __shfl_xor(sq, m);
    if (lane == 0) red[wid] = sq;
    __syncthreads();
    const float xn = red[0] + red[1] + red[2] + red[3];
    float p = 0.f;
#pragma unroll
    for (int jj = 0; jj < 8; jj++){
      const int col = jj * 64 + seg * 8;
      bf16x8 m8 = *(const bf16x8*)&mus[cc][col];
      const float* xv = &xs[col];
#pragma unroll
      for (int e = 0; e < 8; e++) p += xv[e] * (float)m8[e];
    }
#pragma unroll
    for (int m = 1; m < 8; m <<= 1) p += __shfl_xor(p, m);
    if (seg == 0) dots[cc] = p;
    __syncthreads();
    if (tid < 32){
      const float dist = xn + munorm[tid] - 2.f * dots[tid];
      const float lg = -dist * 0.1f;
      float mx = lg;
#pragma unroll
      for (int m = 1; m < 32; m <<= 1) mx = fmaxf(mx, __shfl_xor(mx, m, 32));
      const float z = __expf(lg - mx);
      float s = z;
#pragma unroll
      for (int m = 1; m < 32; m <<= 1) s += __shfl_xor(s, m, 32);
      out[row * 32 + tid] = logf(z / s + EPSF);
    }
    __syncthreads();
  }
}

// ---------------------------------------------------------------------------
__global__ __launch_bounds__(256)
void k_hmm(const float* __restrict__ lza, const float* __restrict__ pi,
           const float* __restrict__ A, float* __restrict__ cp, float* __restrict__ ent)
{
  __shared__ float As[32][33];
  const int tid = threadIdx.x;
  for (int i = tid; i < 1024; i += 256) As[i >> 5][i & 31] = A[i];
  __syncthreads();
  const int j = tid & 31;
  const long n = (long)blockIdx.x * 8 + (tid >> 5);
  const float* lz = lza + n * 2048;

  float c = logf(pi[j] + EPSF) + lz[j];
  {
    float mx = c;
#pragma unroll
    for (int m = 1; m < 32; m <<= 1) mx = fmaxf(mx, __shfl_xor(mx, m, 32));
    float z = __expf(c - mx), s = z;
#pragma unroll
    for (int m = 1; m < 32; m <<= 1) s += __shfl_xor(s, m, 32);
    c = z / s;
  }
  cp[n * 2048 + j] = c;
  float ea = -c * logf(c + EPSF);

  for (int p = 1; p < 64; p++){
    float y = 0.f;
#pragma unroll
    for (int i = 0; i < 32; i++) y += __shfl(c, i, 32) * As[i][j];
    float t = logf(y + EPSF) + lz[p * 32 + j];
    float mx = t;
#pragma unroll
    for (int m = 1; m < 32; m <<= 1) mx = fmaxf(mx, __shfl_xor(mx, m, 32));
    float z = __expf(t - mx), s = z;
#pragma unroll
    for (int m = 1; m < 32; m <<= 1) s += __shfl_xor(s, m, 32);
    c = z / s;
    cp[n * 2048 + p * 32 + j] = c;
    ea += -c * logf(c + EPSF);
  }
#pragma unroll
  for (int m = 1; m < 32; m <<= 1) ea += __shfl_xor(ea, m, 32);
  if (j == 0) atomicAdd(ent, ea * (1.f / 131072.f));
}

// ---------------------------------------------------------------------------
extern "C" void kernel_launch(void* const* d_in, const int* in_sizes, int n_in,
                              void* d_out, int out_size, void* d_ws, size_t ws_size,
                              hipStream_t stream)
{
  (void)in_sizes; (void)n_in; (void)out_size; (void)ws_size;
  const float* in_series = (const float*)d_in[0];
  const float* pi    = (const float*)d_in[1];
  const float* Amat  = (const float*)d_in[2];
  const float* qkv_w = (const float*)d_in[3];
  const float* qkv_b = (const float*)d_in[4];
  const float* out_w = (const float*)d_in[5];
  const float* out_b = (const float*)d_in[6];
  const float* ln1_w = (const float*)d_in[7];
  const float* ln1_b = (const float*)d_in[8];
  const float* ff1_w = (const float*)d_in[9];
  const float* ff1_b = (const float*)d_in[10];
  const float* ff2_w = (const float*)d_in[11];
  const float* ff2_b = (const float*)d_in[12];
  const float* ln2_w = (const float*)d_in[13];
  const float* ln2_b = (const float*)d_in[14];
  const float* mus   = (const float*)d_in[15];

  char* ws = (char*)d_ws;
  bf16* region0 = (bf16*)(ws);                         // 512MB: qkv / ffmid
  bf16* xb      = (bf16*)(ws + 536870912L);            // 128MB
  bf16* oproj   = (bf16*)(ws + 671088640L);            // 128MB
  bf16* w_qkv   = (bf16*)(ws + 805306368L);
  bf16* w_out   = (bf16*)(ws + 810024960L);
  bf16* w_ff1   = (bf16*)(ws + 811597824L);
  bf16* w_ff2   = (bf16*)(ws + 817889280L);
  bf16* mubf    = (bf16*)(ws + 824180736L);
  float* munorm = (float*)(ws + 824213504L);
  float* logza  = (float*)(ws);                        // aliases region0

  float* out_f = (float*)d_out;
  float* cp    = out_f;
  float* emb   = out_f + 4194304L;
  float* o_pi  = out_f + 71303168L;
  float* o_A   = out_f + 71303200L;
  float* o_ent = out_f + 71304224L;

  k_f2bf<<<8192, 256, 0, stream>>>(in_series, xb, 67108864L);
  k_f2bf<<<1024, 256, 0, stream>>>(qkv_w, w_qkv, 2359296L);
  k_f2bf<<<1024, 256, 0, stream>>>(out_w, w_out, 786432L);
  k_f2bf<<<1024, 256, 0, stream>>>(ff1_w, w_ff1, 3145728L);
  k_f2bf<<<1024, 256, 0, stream>>>(ff2_w, w_ff2, 3145728L);
  k_mu<<<32, 256, 0, stream>>>(mus, mubf, munorm);

  for (int l = 0; l < 3; l++){
    // qkv = x @ qkv_w^T + b   -> region0 [131072][1536]
    gemm256<0><<<3072, 512, 0, stream>>>(xb, 512, w_qkv + (long)l * 786432L,
                                         qkv_b + (long)l * 1536, region0, 512, 6);
    attention<<<16384, 256, 0, stream>>>(region0);
    // o @ out_w^T + b -> oproj
    gemm256<0><<<1024, 512, 0, stream>>>(region0, 1536, w_out + (long)l * 262144L,
                                         out_b + (long)l * 512, oproj, 512, 2);
    resid_ln<<<32768, 256, 0, stream>>>(xb, oproj, ln1_w + (long)l * 512,
                                        ln1_b + (long)l * 512, xb, nullptr);
    // ffmid = relu(x @ ff1_w^T + b) -> region0 [131072][2048]
    gemm256<1><<<4096, 512, 0, stream>>>(xb, 512, w_ff1 + (long)l * 1048576L,
                                         ff1_b + (long)l * 2048, region0, 512, 8);
    // ffout = ffmid @ ff2_w^T + b -> oproj
    gemm256<0><<<1024, 512, 0, stream>>>(region0, 2048, w_ff2 + (long)l * 1048576L,
                                         ff2_b + (long)l * 512, oproj, 2048, 2);
    // last layer: fuse f32 emb_ts output into the LN
    resid_ln<<<32768, 256, 0, stream>>>(xb, oproj, ln2_w + (long)l * 512,
                                        ln2_b + (long)l * 512, xb,
                                        (l == 2) ? emb : nullptr);
  }

  cluster_logza<<<8192, 256, 0, stream>>>(xb, mubf, munorm, logza);
  hipMemsetAsync(o_ent, 0, 4, stream);
  k_hmm<<<256, 256, 0, stream>>>(logza, pi, Amat, cp, o_ent);
  hipMemcpyAsync(o_pi, pi, 32 * sizeof(float), hipMemcpyDeviceToDevice, stream);
  hipMemcpyAsync(o_A, Amat, 1024 * sizeof(float), hipMemcpyDeviceToDevice, stream);
}